// Round 13
// baseline (613.976 us; speedup 1.0000x reference)
//
#include <hip/hip_runtime.h>
#include <hip/hip_bf16.h>
#include <math.h>

#define HDIM   256
#define NHEAD  4
#define LLAY   4
#define TLAY   4
#define KMAXC  10
#define MAXD   32
#define BATCH  64
#define MSUB   32
#define KNODE  32
#define SSUB   2048
#define NNODE  65536
#define NEDGE  131072
#define EPSPER 64
#define EDN    5
#define BSTR   264   // bondL padded stride (floats)

typedef unsigned short u16;
typedef __attribute__((ext_vector_type(8))) short bf16x8;
typedef __attribute__((ext_vector_type(4))) float f32x4;

__device__ __forceinline__ float us2f(u16 u) {
    union { unsigned int i; float f; } x; x.i = ((unsigned int)u) << 16; return x.f;
}
__device__ __forceinline__ u16 f2us(float v) {
    union { float f; unsigned int i; } x; x.f = v;
    unsigned int u = x.i;
    u += 0x7fffu + ((u >> 16) & 1u);   // RNE
    return (u16)(u >> 16);
}
__device__ __forceinline__ float finite_or_zero(float v) {
    return (v == v && fabsf(v) <= 3.0e38f) ? v : 0.0f;
}
__device__ __forceinline__ void gll16(const u16* g, u16* l) {
    __builtin_amdgcn_global_load_lds(
        (const __attribute__((address_space(1))) unsigned int*)g,
        (__attribute__((address_space(3))) unsigned int*)l, 16, 0, 0);
}

// ---------------------------------------------------------------------------
__global__ __launch_bounds__(256) void k_csr(
    const int* __restrict__ src, const int* __restrict__ dst,
    const int* __restrict__ eid, u16* __restrict__ perm, u16* __restrict__ off)
{
    __shared__ int sL[4][64], dL[4][64], eL[4][64];
    int wave = threadIdx.x >> 6, lane = threadIdx.x & 63;
    int sgi = blockIdx.x * 4 + wave;
    sL[wave][lane] = src[sgi * 64 + lane] - sgi * KNODE;
    dL[wave][lane] = dst[sgi * 64 + lane] - sgi * KNODE;
    eL[wave][lane] = eid[sgi * 64 + lane];
    __syncthreads();
    if (lane < 32) {
        int cnt = 0;
        for (int e = 0; e < 64; ++e) cnt += (dL[wave][e] == lane) ? 1 : 0;
        int incl = cnt;
        #pragma unroll
        for (int d = 1; d < 32; d <<= 1) {
            int v = __shfl_up(incl, d, 64);
            if (lane >= d) incl += v;
        }
        int start = incl - cnt;
        off[sgi * 32 + lane] = (u16)start;
        int pos = start;
        for (int e = 0; e < 64; ++e) {
            if (dL[wave][e] == lane) {
                perm[sgi * 64 + pos] = (u16)((sL[wave][e] << 3) | eL[wave][e]);
                ++pos;
            }
        }
    }
}

// ---------------------------------------------------------------------------
__global__ __launch_bounds__(256) void k_wtrans(
    const float* __restrict__ W, u16* __restrict__ WT, int K, int N)
{
    __shared__ float til[32][33];
    int k0 = blockIdx.x * 32, n0 = blockIdx.y * 32, s = blockIdx.z;
    const float* Wb = W + (size_t)s * K * N;
    u16* Tb = WT + (size_t)s * N * K;
    int j = threadIdx.x & 31, i0 = threadIdx.x >> 5;
    #pragma unroll
    for (int it = 0; it < 4; ++it) {
        int i = i0 + it * 8;
        til[i][j] = Wb[(size_t)(k0 + i) * N + n0 + j];
    }
    __syncthreads();
    #pragma unroll
    for (int it = 0; it < 4; ++it) {
        int i = i0 + it * 8;
        Tb[(size_t)(n0 + i) * K + k0 + j] = f2us(til[j][i]);
    }
}

// ---------------------------------------------------------------------------
// Fully-fused GNN: 1 subgraph (32 rows) per block, grid 2048, LDS ~22 KB.
// hz swizzle: logical chunk cc of row r at physical (cc ^ (r&7))*16B.
// Edge phase chunk map cc = q*8+g8 (bank spread by g8); bond stride 264.
__global__ __launch_bounds__(256, 3) void k_gnn4(
    const int* __restrict__ x_ids, const int* __restrict__ dist,
    const int* __restrict__ nodes, const float* __restrict__ lp,
    const float* __restrict__ atom_emb, const float* __restrict__ dist_emb,
    const float* __restrict__ logp_W, const float* __restrict__ logp_b,
    const u16* __restrict__ perm, const u16* __restrict__ off,
    const float* __restrict__ bond_emb, const float* __restrict__ eps_arr,
    const float* __restrict__ b1a, const float* __restrict__ b2a,
    const u16* __restrict__ W1T, const u16* __restrict__ W2T,
    float* __restrict__ x)
{
    __shared__ __align__(16) unsigned char smem[22144];
    u16*   hz    = (u16*)smem;                        // 16384
    float* bondL = (float*)(smem + 16384);            // 5*264*4 = 5280
    u16*   permL = (u16*)(smem + 21760);              // 64 u16
    u16*   offL  = (u16*)(smem + 21888);              // 32 u16
    float* validL= (float*)(smem + 21952);            // 32 f32
    float* epsL  = (float*)(smem + 22080);            // 4 f32

    int tid = threadIdx.x, lane = tid & 63, wave = tid >> 6;
    int sg = blockIdx.x, row0 = sg * 32;
    int fr = lane & 15, quad = lane >> 4;

    for (int i = tid; i < EDN * BSTR; i += 256) {
        int r = i / BSTR, c = i - r * BSTR;
        bondL[i] = (c < 256) ? bond_emb[r * 256 + c] : 0.f;
    }
    if (tid < 64) permL[tid] = perm[sg * 64 + tid];
    if (tid < 32) {
        offL[tid] = off[sg * 32 + tid];
        validL[tid] = (nodes[row0 + tid] >= 0) ? 1.0f : 0.0f;
    }
    if (tid < 4) epsL[tid] = eps_arr[tid];

    {   // h init: 8 threads/row, 4 chunks each
        int m = tid >> 3, t8 = tid & 7;
        int rg = row0 + m;
        float valid = (nodes[rg] >= 0) ? 1.0f : 0.0f;
        float lpv = finite_or_zero(lp[rg >> 5]);
        int dc = dist[rg]; dc = dc < 0 ? 0 : (dc > MAXD ? MAXD : dc);
        int xid = x_ids[rg];
        #pragma unroll
        for (int k = 0; k < 4; ++k) {
            int cc = t8 * 4 + k, c = cc * 8;
            float4 a0 = *reinterpret_cast<const float4*>(atom_emb + xid * 256 + c);
            float4 a1 = *reinterpret_cast<const float4*>(atom_emb + xid * 256 + c + 4);
            float4 d0 = *reinterpret_cast<const float4*>(dist_emb + dc * 256 + c);
            float4 d1 = *reinterpret_cast<const float4*>(dist_emb + dc * 256 + c + 4);
            float4 w0 = *reinterpret_cast<const float4*>(logp_W + c);
            float4 w1 = *reinterpret_cast<const float4*>(logp_W + c + 4);
            float4 p0 = *reinterpret_cast<const float4*>(logp_b + c);
            float4 p1 = *reinterpret_cast<const float4*>(logp_b + c + 4);
            union { bf16x8 v; ushort4 h[2]; } o;
            o.h[0] = (ushort4){
                f2us((a0.x + d0.x + fmaxf(lpv * w0.x + p0.x, 0.f)) * valid),
                f2us((a0.y + d0.y + fmaxf(lpv * w0.y + p0.y, 0.f)) * valid),
                f2us((a0.z + d0.z + fmaxf(lpv * w0.z + p0.z, 0.f)) * valid),
                f2us((a0.w + d0.w + fmaxf(lpv * w0.w + p0.w, 0.f)) * valid) };
            o.h[1] = (ushort4){
                f2us((a1.x + d1.x + fmaxf(lpv * w1.x + p1.x, 0.f)) * valid),
                f2us((a1.y + d1.y + fmaxf(lpv * w1.y + p1.y, 0.f)) * valid),
                f2us((a1.z + d1.z + fmaxf(lpv * w1.z + p1.z, 0.f)) * valid),
                f2us((a1.w + d1.w + fmaxf(lpv * w1.w + p1.w, 0.f)) * valid) };
            *reinterpret_cast<bf16x8*>(hz + m * 256 + ((cc ^ (m & 7)) * 8)) = o.v;
        }
    }
    __syncthreads();

    int rl = tid >> 3, g8 = tid & 7;
    for (int l = 0; l < LLAY; ++l) {
        float ep1 = 1.0f + epsL[l];
        {   // edge phase: register accumulation, chunk map cc = q*8+g8
            int e0 = offL[rl];
            int e1 = (rl < 31) ? offL[rl + 1] : 64;
            float a[32];
            #pragma unroll
            for (int q = 0; q < 32; ++q) a[q] = 0.f;
            for (int j = e0; j < e1; ++j) {
                int ent = permL[j];
                int sl = ent >> 3, be = ent & 7;
                #pragma unroll
                for (int q = 0; q < 4; ++q) {
                    int cc = q * 8 + g8;
                    union { bf16x8 v; u16 s[8]; } hv;
                    hv.v = *reinterpret_cast<const bf16x8*>(
                        hz + sl * 256 + ((cc ^ (sl & 7)) * 8));
                    const float* bp = bondL + be * BSTR + cc * 8;
                    float4 bo0 = *reinterpret_cast<const float4*>(bp);
                    float4 bo1 = *reinterpret_cast<const float4*>(bp + 4);
                    a[q*8+0] += fmaxf(us2f(hv.s[0]) + bo0.x, 0.f);
                    a[q*8+1] += fmaxf(us2f(hv.s[1]) + bo0.y, 0.f);
                    a[q*8+2] += fmaxf(us2f(hv.s[2]) + bo0.z, 0.f);
                    a[q*8+3] += fmaxf(us2f(hv.s[3]) + bo0.w, 0.f);
                    a[q*8+4] += fmaxf(us2f(hv.s[4]) + bo1.x, 0.f);
                    a[q*8+5] += fmaxf(us2f(hv.s[5]) + bo1.y, 0.f);
                    a[q*8+6] += fmaxf(us2f(hv.s[6]) + bo1.z, 0.f);
                    a[q*8+7] += fmaxf(us2f(hv.s[7]) + bo1.w, 0.f);
                }
            }
            __syncthreads();
            #pragma unroll
            for (int q = 0; q < 4; ++q) {
                int cc = q * 8 + g8;
                u16* ptr = hz + rl * 256 + ((cc ^ (rl & 7)) * 8);
                union { bf16x8 v; u16 s[8]; } hv, ov;
                hv.v = *reinterpret_cast<const bf16x8*>(ptr);
                #pragma unroll
                for (int k = 0; k < 8; ++k)
                    ov.s[k] = f2us(ep1 * us2f(hv.s[k]) + a[q * 8 + k]);
                *reinterpret_cast<bf16x8*>(ptr) = ov.v;
            }
        }
        __syncthreads();

        // phase 1: zr = relu(z @ W1 + b1); wave owns n-rows [wave*64, +64)
        const u16* W1 = W1T + l * 65536;
        const float* b1 = b1a + l * 256;
        f32x4 acc[4][2];
        #pragma unroll
        for (int i = 0; i < 4; ++i) { acc[i][0] = (f32x4){0,0,0,0}; acc[i][1] = (f32x4){0,0,0,0}; }
        #pragma unroll
        for (int kc = 0; kc < 8; ++kc) {
            bf16x8 bfv[2];
            #pragma unroll
            for (int j = 0; j < 2; ++j) {
                int m = j * 16 + fr;
                bfv[j] = *reinterpret_cast<const bf16x8*>(hz + m * 256 + (((kc * 4 + quad) ^ (m & 7)) * 8));
            }
            #pragma unroll
            for (int i = 0; i < 4; ++i) {
                bf16x8 wf = *reinterpret_cast<const bf16x8*>(
                    W1 + (size_t)(wave * 64 + i * 16 + fr) * 256 + kc * 32 + quad * 8);
                acc[i][0] = __builtin_amdgcn_mfma_f32_16x16x32_bf16(wf, bfv[0], acc[i][0], 0, 0, 0);
                acc[i][1] = __builtin_amdgcn_mfma_f32_16x16x32_bf16(wf, bfv[1], acc[i][1], 0, 0, 0);
            }
        }
        __syncthreads();
        #pragma unroll
        for (int i = 0; i < 4; ++i) {
            int n1b = wave * 64 + i * 16 + quad * 4;
            float4 bb = *reinterpret_cast<const float4*>(b1 + n1b);
            #pragma unroll
            for (int j = 0; j < 2; ++j) {
                int m = j * 16 + fr;
                ushort4 o = { f2us(fmaxf(acc[i][j][0] + bb.x, 0.f)),
                              f2us(fmaxf(acc[i][j][1] + bb.y, 0.f)),
                              f2us(fmaxf(acc[i][j][2] + bb.z, 0.f)),
                              f2us(fmaxf(acc[i][j][3] + bb.w, 0.f)) };
                *reinterpret_cast<ushort4*>(hz + m * 256 + (((n1b >> 3) ^ (m & 7)) * 8) + (n1b & 7)) = o;
            }
        }
        __syncthreads();

        // phase 2: h' = (zr @ W2 + b2) * valid
        const u16* W2 = W2T + l * 65536;
        const float* b2 = b2a + l * 256;
        #pragma unroll
        for (int i = 0; i < 4; ++i) { acc[i][0] = (f32x4){0,0,0,0}; acc[i][1] = (f32x4){0,0,0,0}; }
        #pragma unroll
        for (int kc = 0; kc < 8; ++kc) {
            bf16x8 bfv[2];
            #pragma unroll
            for (int j = 0; j < 2; ++j) {
                int m = j * 16 + fr;
                bfv[j] = *reinterpret_cast<const bf16x8*>(hz + m * 256 + (((kc * 4 + quad) ^ (m & 7)) * 8));
            }
            #pragma unroll
            for (int i = 0; i < 4; ++i) {
                bf16x8 wf = *reinterpret_cast<const bf16x8*>(
                    W2 + (size_t)(wave * 64 + i * 16 + fr) * 256 + kc * 32 + quad * 8);
                acc[i][0] = __builtin_amdgcn_mfma_f32_16x16x32_bf16(wf, bfv[0], acc[i][0], 0, 0, 0);
                acc[i][1] = __builtin_amdgcn_mfma_f32_16x16x32_bf16(wf, bfv[1], acc[i][1], 0, 0, 0);
            }
        }
        __syncthreads();
        if (l < LLAY - 1) {
            #pragma unroll
            for (int i = 0; i < 4; ++i) {
                int n2b = wave * 64 + i * 16 + quad * 4;
                float4 bb = *reinterpret_cast<const float4*>(b2 + n2b);
                #pragma unroll
                for (int j = 0; j < 2; ++j) {
                    int m = j * 16 + fr;
                    float vm = validL[m];
                    ushort4 o = { f2us((acc[i][j][0] + bb.x) * vm),
                                  f2us((acc[i][j][1] + bb.y) * vm),
                                  f2us((acc[i][j][2] + bb.z) * vm),
                                  f2us((acc[i][j][3] + bb.w) * vm) };
                    *reinterpret_cast<ushort4*>(hz + m * 256 + (((n2b >> 3) ^ (m & 7)) * 8) + (n2b & 7)) = o;
                }
            }
            __syncthreads();
        } else {
            if (fr == 0) {   // root row m = 0 only
                float vm = validL[0];
                #pragma unroll
                for (int i = 0; i < 4; ++i) {
                    int n2b = wave * 64 + i * 16 + quad * 4;
                    float4 bb = *reinterpret_cast<const float4*>(b2 + n2b);
                    float4 o = { (acc[i][0][0] + bb.x) * vm, (acc[i][0][1] + bb.y) * vm,
                                 (acc[i][0][2] + bb.z) * vm, (acc[i][0][3] + bb.w) * vm };
                    *reinterpret_cast<float4*>(x + (size_t)sg * 256 + n2b) = o;
                }
            }
        }
    }
}

// ---------------------------------------------------------------------------
__global__ __launch_bounds__(1024) void k_bias(
    const int* __restrict__ nodes, const float* __restrict__ lp,
    const float* __restrict__ ovl_emb, const float* __restrict__ alpha_p,
    float* __restrict__ bias)
{
    int b = blockIdx.x, tid = threadIdx.x;
    __shared__ int nd[32][32];
    __shared__ unsigned int bmv[32][17];
    __shared__ float lpc[32];
    __shared__ float emb[16];
    nd[tid >> 5][tid & 31] = nodes[b * 1024 + tid];
    if (tid < 512) bmv[tid >> 4][tid & 15] = 0u;
    if (tid < 32) {
        float l = finite_or_zero(lp[b * 32 + tid]);
        l = l < -30.f ? -30.f : (l > 0.f ? 0.f : l);
        lpc[tid] = l;
    }
    if (tid >= 64 && tid < 64 + KMAXC + 1) emb[tid - 64] = ovl_emb[tid - 64];
    __syncthreads();
    int own = nd[tid >> 5][tid & 31];
    if (own >= 0) atomicOr(&bmv[tid >> 5][own >> 5], 1u << (own & 31));
    __syncthreads();
    int i = tid >> 5, j = tid & 31;
    float alpha = alpha_p[0];
    int cnt = 0;
    #pragma unroll
    for (int k = 0; k < 32; ++k) {
        int nk = nd[i][k];
        if (nk >= 0) cnt += (int)((bmv[j][nk >> 5] >> (nk & 31)) & 1u);
    }
    bias[b * 1024 + tid] = emb[cnt > KMAXC ? KMAXC : cnt] - alpha * lpc[j];
}

// ---------------------------------------------------------------------------
// LN(X) @ BT^T fused GEMM, 32x64 tile. A LDS-resident (swizzled), B streamed
// dbuf with staging-side swizzle (kchunk ^ (row>>1)&3) to kill bank conflicts.
__global__ __launch_bounds__(256) void k_gemmA_ln(
    const float* __restrict__ X, const u16* __restrict__ BT,
    const float* __restrict__ ln_g, const float* __restrict__ ln_b,
    const float* __restrict__ bias, u16* __restrict__ C,
    int N, int act)
{
    __shared__ __align__(16) u16 As[32 * 256];     // 16 KB swizzled
    __shared__ __align__(16) u16 Bs[2][64 * 32];   // 4 KB each
    int tid = threadIdx.x, lane = tid & 63, wave = tid >> 6;
    int wm = wave >> 1, wn = wave & 1;
    int bm = blockIdx.y * 32, bn = blockIdx.x * 64;
    int fr = lane & 15, quad = lane >> 4;

    int srow = lane >> 2, skq = lane & 3;          // staging row/chunk
    const u16* gB = BT + (size_t)(bn + wave * 16 + srow) * 256
                       + (skq ^ ((srow >> 1) & 3)) * 8;
    gll16(gB, &Bs[0][wave * 512]);

    #pragma unroll
    for (int rr = 0; rr < 8; ++rr) {
        int r = wave * 8 + rr;
        float4 xv = *reinterpret_cast<const float4*>(X + (size_t)(bm + r) * 256 + lane * 4);
        float s = xv.x + xv.y + xv.z + xv.w;
        #pragma unroll
        for (int o2 = 32; o2 > 0; o2 >>= 1) s += __shfl_xor(s, o2);
        float mu = s * (1.0f / 256.0f);
        float d0 = xv.x - mu, d1 = xv.y - mu, d2 = xv.z - mu, d3 = xv.w - mu;
        float sq = d0 * d0 + d1 * d1 + d2 * d2 + d3 * d3;
        #pragma unroll
        for (int o2 = 32; o2 > 0; o2 >>= 1) sq += __shfl_xor(sq, o2);
        float rs = rsqrtf(sq * (1.0f / 256.0f) + 1e-5f);
        int c = lane * 4;
        float4 gv = *reinterpret_cast<const float4*>(ln_g + c);
        float4 bv = *reinterpret_cast<const float4*>(ln_b + c);
        ushort4 o = { f2us(d0 * rs * gv.x + bv.x), f2us(d1 * rs * gv.y + bv.y),
                      f2us(d2 * rs * gv.z + bv.z), f2us(d3 * rs * gv.w + bv.w) };
        *reinterpret_cast<ushort4*>(As + r * 256 + (((lane >> 1) ^ (r & 7)) * 8) + (lane & 1) * 4) = o;
    }
    __syncthreads();

    f32x4 acc[2];
    acc[0] = (f32x4){0,0,0,0}; acc[1] = (f32x4){0,0,0,0};
    for (int kc = 0; kc < 8; ++kc) {
        int buf = kc & 1;
        if (kc < 7) gll16(gB + (kc + 1) * 32, &Bs[buf ^ 1][wave * 512]);
        int am = wm * 16 + fr;
        bf16x8 af = *reinterpret_cast<const bf16x8*>(
            As + am * 256 + (((kc * 4 + quad) ^ (am & 7)) * 8));
        bf16x8 bfr[2];
        #pragma unroll
        for (int j = 0; j < 2; ++j) {
            int br = wn * 32 + j * 16 + fr;
            bfr[j] = *reinterpret_cast<const bf16x8*>(
                &Bs[buf][br * 32 + (quad ^ ((br >> 1) & 3)) * 8]);
        }
        acc[0] = __builtin_amdgcn_mfma_f32_16x16x32_bf16(af, bfr[0], acc[0], 0, 0, 0);
        acc[1] = __builtin_amdgcn_mfma_f32_16x16x32_bf16(af, bfr[1], acc[1], 0, 0, 0);
        __syncthreads();
    }
    int crow0 = bm + wm * 16 + quad * 4;
    int ccol0 = bn + wn * 32 + fr;
    #pragma unroll
    for (int r = 0; r < 4; ++r) {
        int m = crow0 + r;
        #pragma unroll
        for (int j = 0; j < 2; ++j) {
            int n = ccol0 + j * 16;
            float v = acc[j][r];
            if (bias) v += bias[n];
            if (act == 2) v = 0.5f * v * (1.0f + erff(v * 0.70710678118654752f));
            C[(size_t)m * N + n] = f2us(v);
        }
    }
}

// ---------------------------------------------------------------------------
// bf16 GEMM 32x64 tile, dbuf gll16 staging with swizzle; f32 out + resid.
__global__ __launch_bounds__(256) void k_gemmB(
    const u16* __restrict__ A, const u16* __restrict__ BT,
    const float* __restrict__ bias, float* __restrict__ Cout,
    const float* __restrict__ resid, int M, int K, int N)
{
    __shared__ __align__(16) u16 As[2][32 * 32];   // 2 KB each
    __shared__ __align__(16) u16 Bs[2][64 * 32];   // 4 KB each
    int tid = threadIdx.x, lane = tid & 63, wave = tid >> 6;
    int wm = wave >> 1, wn = wave & 1;
    int bm = blockIdx.y * 32, bn = blockIdx.x * 64;
    int fr = lane & 15, quad = lane >> 4;
    int srow = lane >> 2, skq = lane & 3;
    int koff = (skq ^ ((srow >> 1) & 3)) * 8;
    const u16* gA = A + (size_t)(bm + (wave & 1) * 16 + srow) * K + koff;
    const u16* gB = BT + (size_t)(bn + wave * 16 + srow) * K + koff;
    if (wave < 2) gll16(gA, &As[0][wave * 512]);
    gll16(gB, &Bs[0][wave * 512]);
    f32x4 acc[2];
    acc[0] = (f32x4){0,0,0,0}; acc[1] = (f32x4){0,0,0,0};
    int nit = K >> 5;
    __syncthreads();
    for (int it = 0; it < nit; ++it) {
        int buf = it & 1;
        if (it + 1 < nit) {
            int k0 = (it + 1) * 32;
            if (wave < 2) gll16(gA + k0, &As[buf ^ 1][wave * 512]);
            gll16(gB + k0, &Bs[buf ^ 1][wave * 512]);
        }
        int am = wm * 16 + fr;
        bf16x8 af = *reinterpret_cast<const bf16x8*>(
            &As[buf][am * 32 + (quad ^ ((am >> 1) & 3)) * 8]);
        bf16x8 bfr[2];
        #pragma unroll
        for (int j = 0; j < 2; ++j) {
            int br = wn * 32 + j * 16 + fr;
            bfr[j] = *reinterpret_cast<const bf16x8*>(
                &Bs[buf][br * 32 + (quad ^ ((br >> 1) & 3)) * 8]);
        }
        acc[0] = __builtin_amdgcn_mfma_f32_16x16x32_bf16(af, bfr[0], acc[0], 0, 0, 0);
        acc[1] = __builtin_amdgcn_mfma_f32_16x16x32_bf16(af, bfr[1], acc[1], 0, 0, 0);
        __syncthreads();
    }
    int crow0 = bm + wm * 16 + quad * 4;
    int ccol0 = bn + wn * 32 + fr;
    #pragma unroll
    for (int r = 0; r < 4; ++r) {
        int m = crow0 + r;
        #pragma unroll
        for (int j = 0; j < 2; ++j) {
            int n = ccol0 + j * 16;
            float v = acc[j][r] + bias[n] + resid[(size_t)m * N + n];
            Cout[(size_t)m * N + n] = v;
        }
    }
}

// ---------------------------------------------------------------------------
// Attention per (batch, head) — verified R8 body.
__global__ __launch_bounds__(256) void k_attn(
    const u16* __restrict__ qkv, const float* __restrict__ bias, u16* __restrict__ o)
{
    int b = blockIdx.x >> 2, hh = blockIdx.x & 3;
    __shared__ float qs[32][65], ks[32][65], vs[32][65];
    __shared__ float sc[32][33];
    int tid = threadIdx.x;
    #pragma unroll
    for (int u = 0; u < 8; ++u) {
        int idx = tid + u * 256;
        int i = idx >> 6, d = idx & 63;
        size_t base = (size_t)(b * 32 + i) * 768;
        qs[i][d] = us2f(qkv[base + hh * 64 + d]);
        ks[i][d] = us2f(qkv[base + 256 + hh * 64 + d]);
        vs[i][d] = us2f(qkv[base + 512 + hh * 64 + d]);
    }
    __syncthreads();
    #pragma unroll
    for (int u = 0; u < 4; ++u) {
        int p = tid + u * 256;
        int i = p >> 5, j = p & 31;
        float s = 0.f;
        #pragma unroll
        for (int d = 0; d < 64; ++d) s += qs[i][d] * ks[j][d];
        sc[i][j] = s * 0.125f + bias[b * 1024 + i * 32 + j];
    }
    __syncthreads();
    if (tid < 32) {
        int i = tid;
        float m = -1e30f;
        for (int j = 0; j < 32; ++j) m = fmaxf(m, sc[i][j]);
        float sum = 0.f;
        for (int j = 0; j < 32; ++j) { float e = expf(sc[i][j] - m); sc[i][j] = e; sum += e; }
        float inv = 1.0f / sum;
        for (int j = 0; j < 32; ++j) sc[i][j] *= inv;
    }
    __syncthreads();
    #pragma unroll
    for (int u = 0; u < 8; ++u) {
        int idx = tid + u * 256;
        int i = idx >> 6, d = idx & 63;
        float a = 0.f;
        #pragma unroll
        for (int j = 0; j < 32; ++j) a += sc[i][j] * vs[j][d];
        o[(size_t)(b * 32 + i) * 256 + hh * 64 + d] = f2us(a);
    }
}

// ---------------------------------------------------------------------------
// Final LN + softmax(-lp_c)-weighted sum (verified R11 body).
__global__ __launch_bounds__(256) void k_fin(
    const float* __restrict__ x, const float* __restrict__ lp,
    const float* __restrict__ lnout_g, const float* __restrict__ lnout_b,
    float* __restrict__ out)
{
    __shared__ __align__(16) float xlnf[32 * 260];
    __shared__ float wfin[32];
    int tid = threadIdx.x, lane = tid & 63, wave = tid >> 6;
    int b = blockIdx.x;
    #pragma unroll
    for (int rr = 0; rr < 8; ++rr) {
        int row = wave * 8 + rr;
        float4 xv = *reinterpret_cast<const float4*>(x + (size_t)(b * 32 + row) * 256 + lane * 4);
        float s = xv.x + xv.y + xv.z + xv.w;
        #pragma unroll
        for (int o2 = 32; o2 > 0; o2 >>= 1) s += __shfl_xor(s, o2);
        float mu = s * (1.0f / 256.0f);
        float d0 = xv.x - mu, d1 = xv.y - mu, d2 = xv.z - mu, d3 = xv.w - mu;
        float sq = d0 * d0 + d1 * d1 + d2 * d2 + d3 * d3;
        #pragma unroll
        for (int o2 = 32; o2 > 0; o2 >>= 1) sq += __shfl_xor(sq, o2);
        float rs = rsqrtf(sq * (1.0f / 256.0f) + 1e-5f);
        int c = lane * 4;
        float4 gv = *reinterpret_cast<const float4*>(lnout_g + c);
        float4 bv = *reinterpret_cast<const float4*>(lnout_b + c);
        float4 o = { d0 * rs * gv.x + bv.x, d1 * rs * gv.y + bv.y,
                     d2 * rs * gv.z + bv.z, d3 * rs * gv.w + bv.w };
        *reinterpret_cast<float4*>(xlnf + row * 260 + c) = o;
    }
    __syncthreads();
    if (tid == 0) {
        float l2[32];
        float m = -1e30f;
        for (int i = 0; i < 32; ++i) {
            float l = finite_or_zero(lp[b * 32 + i]);
            l = l < -30.f ? -30.f : (l > 0.f ? 0.f : l);
            l2[i] = -l;
            m = fmaxf(m, -l);
        }
        float s = 0.f;
        for (int i = 0; i < 32; ++i) { float e = expf(l2[i] - m); wfin[i] = e; s += e; }
        float inv = 1.0f / s;
        for (int i = 0; i < 32; ++i) wfin[i] *= inv;
    }
    __syncthreads();
    float a = 0.f;
    for (int i = 0; i < 32; ++i) a += wfin[i] * xlnf[i * 260 + tid];
    out[(size_t)b * 256 + tid] = a;
}

// ---------------------------------------------------------------------------
extern "C" void kernel_launch(void* const* d_in, const int* in_sizes, int n_in,
                              void* d_out, int out_size, void* d_ws, size_t ws_size,
                              hipStream_t stream)
{
    const int*   x_ids    = (const int*)d_in[0];
    const int*   edge_ids = (const int*)d_in[1];
    const int*   srcp     = (const int*)d_in[2];
    const int*   dstp     = (const int*)d_in[3];
    const int*   nodes    = (const int*)d_in[4];
    const int*   dist     = (const int*)d_in[5];
    const float* lp       = (const float*)d_in[6];
    const float* atom_emb = (const float*)d_in[7];
    const float* bond_emb = (const float*)d_in[8];
    const float* dist_emb = (const float*)d_in[9];
    const float* logp_W   = (const float*)d_in[10];
    const float* logp_b   = (const float*)d_in[11];
    const float* gnn_eps  = (const float*)d_in[12];
    const float* gnn_W1   = (const float*)d_in[13];
    const float* gnn_b1   = (const float*)d_in[14];
    const float* gnn_W2   = (const float*)d_in[15];
    const float* gnn_b2   = (const float*)d_in[16];
    const float* ln1_g    = (const float*)d_in[17];
    const float* ln1_b    = (const float*)d_in[18];
    const float* qkv_W    = (const float*)d_in[19];
    const float* out_W    = (const float*)d_in[20];
    const float* out_b    = (const float*)d_in[21];
    const float* ln2_g    = (const float*)d_in[22];
    const float* ln2_b    = (const float*)d_in[23];
    const float* f1_W     = (const float*)d_in[24];
    const float* f1_b     = (const float*)d_in[25];
    const float* f2_W     = (const float*)d_in[26];
    const float* f2_b     = (const float*)d_in[27];
    const float* lnout_g  = (const float*)d_in[28];
    const float* lnout_b  = (const float*)d_in[29];
    const float* ovl_emb  = (const float*)d_in[30];
    const float* alpha    = (const float*)d_in[31];

    char* ws = (char*)d_ws;
    u16*   gW1T  = (u16*)(ws + 100663296ull);
    u16*   gW2T  = (u16*)(ws + 100663296ull + 524288ull);
    u16*   permW = (u16*)(ws + 100663296ull + 1048576ull);
    u16*   offW  = (u16*)(ws + 100663296ull + 1310720ull);
    u16*   qkvT  = (u16*)(ws + 33554432ull);
    u16*   outT  = (u16*)(ws + 33554432ull + 1572864ull);
    u16*   f1T   = (u16*)(ws + 33554432ull + 2097152ull);
    u16*   f2T   = (u16*)(ws + 33554432ull + 4194304ull);
    u16*   ob    = (u16*)(ws + 33554432ull + 6291456ull);
    float* biasb = (float*)(ws + 33554432ull + 7340032ull);
    u16*   qkvb  = (u16*)(ws + 33554432ull + 7602176ull);
    u16*   ffh   = (u16*)(ws + 33554432ull + 10747904ull);
    float* x     = (float*)(ws + 67108864ull);

    k_csr<<<SSUB / 4, 256, 0, stream>>>(srcp, dstp, edge_ids, permW, offW);
    k_wtrans<<<dim3(8, 8, 4), 256, 0, stream>>>(gnn_W1, gW1T, 256, 256);
    k_wtrans<<<dim3(8, 8, 4), 256, 0, stream>>>(gnn_W2, gW2T, 256, 256);
    k_gnn4<<<SSUB, 256, 0, stream>>>(
        x_ids, dist, nodes, lp, atom_emb, dist_emb, logp_W, logp_b,
        permW, offW, bond_emb, gnn_eps, gnn_b1, gnn_b2, gW1T, gW2T, x);
    k_wtrans<<<dim3(8, 24, 4), 256, 0, stream>>>(qkv_W, qkvT, 256, 768);
    k_wtrans<<<dim3(8, 8, 4), 256, 0, stream>>>(out_W, outT, 256, 256);
    k_wtrans<<<dim3(8, 32, 4), 256, 0, stream>>>(f1_W, f1T, 256, 1024);
    k_wtrans<<<dim3(32, 8, 4), 256, 0, stream>>>(f2_W, f2T, 1024, 256);
    k_bias<<<BATCH, 1024, 0, stream>>>(nodes, lp, ovl_emb, alpha, biasb);
    for (int t = 0; t < TLAY; ++t) {
        k_gemmA_ln<<<dim3(12, 64), 256, 0, stream>>>(
            x, qkvT + (size_t)t * 768 * 256, ln1_g + t * 256, ln1_b + t * 256,
            nullptr, qkvb, 768, 0);
        k_attn<<<BATCH * NHEAD, 256, 0, stream>>>(qkvb, biasb, ob);
        k_gemmB<<<dim3(4, 64), 256, 0, stream>>>(
            ob, outT + (size_t)t * 65536, out_b + t * 256, x, x, SSUB, 256, 256);
        k_gemmA_ln<<<dim3(16, 64), 256, 0, stream>>>(
            x, f1T + (size_t)t * 1024 * 256, ln2_g + t * 256, ln2_b + t * 256,
            f1_b + t * 1024, ffh, 1024, 2);
        k_gemmB<<<dim3(4, 64), 256, 0, stream>>>(
            ffh, f2T + (size_t)t * 256 * 1024, f2_b + t * 256, x, x, SSUB, 1024, 256);
    }
    k_fin<<<BATCH, 256, 0, stream>>>(x, lp, lnout_g, lnout_b, (float*)d_out);
}

// Round 14
// 525.525 us; speedup vs baseline: 1.1683x; 1.1683x over previous
//
#include <hip/hip_runtime.h>
#include <hip/hip_bf16.h>
#include <math.h>

#define HDIM   256
#define NHEAD  4
#define LLAY   4
#define TLAY   4
#define KMAXC  10
#define MAXD   32
#define BATCH  64
#define MSUB   32
#define KNODE  32
#define SSUB   2048
#define NNODE  65536
#define NEDGE  131072
#define EPSPER 64
#define EDN    5
#define BSTR   264   // bondL padded stride (floats)

typedef unsigned short u16;
typedef __attribute__((ext_vector_type(8))) short bf16x8;
typedef __attribute__((ext_vector_type(4))) float f32x4;

__device__ __forceinline__ float us2f(u16 u) {
    union { unsigned int i; float f; } x; x.i = ((unsigned int)u) << 16; return x.f;
}
__device__ __forceinline__ u16 f2us(float v) {
    union { float f; unsigned int i; } x; x.f = v;
    unsigned int u = x.i;
    u += 0x7fffu + ((u >> 16) & 1u);   // RNE
    return (u16)(u >> 16);
}
__device__ __forceinline__ float finite_or_zero(float v) {
    return (v == v && fabsf(v) <= 3.0e38f) ? v : 0.0f;
}
__device__ __forceinline__ void gll16(const u16* g, u16* l) {
    __builtin_amdgcn_global_load_lds(
        (const __attribute__((address_space(1))) unsigned int*)g,
        (__attribute__((address_space(3))) unsigned int*)l, 16, 0, 0);
}

// ---------------------------------------------------------------------------
__global__ __launch_bounds__(256) void k_csr(
    const int* __restrict__ src, const int* __restrict__ dst,
    const int* __restrict__ eid, u16* __restrict__ perm, u16* __restrict__ off)
{
    __shared__ int sL[4][64], dL[4][64], eL[4][64];
    int wave = threadIdx.x >> 6, lane = threadIdx.x & 63;
    int sgi = blockIdx.x * 4 + wave;
    sL[wave][lane] = src[sgi * 64 + lane] - sgi * KNODE;
    dL[wave][lane] = dst[sgi * 64 + lane] - sgi * KNODE;
    eL[wave][lane] = eid[sgi * 64 + lane];
    __syncthreads();
    if (lane < 32) {
        int cnt = 0;
        for (int e = 0; e < 64; ++e) cnt += (dL[wave][e] == lane) ? 1 : 0;
        int incl = cnt;
        #pragma unroll
        for (int d = 1; d < 32; d <<= 1) {
            int v = __shfl_up(incl, d, 64);
            if (lane >= d) incl += v;
        }
        int start = incl - cnt;
        off[sgi * 32 + lane] = (u16)start;
        int pos = start;
        for (int e = 0; e < 64; ++e) {
            if (dL[wave][e] == lane) {
                perm[sgi * 64 + pos] = (u16)((sL[wave][e] << 3) | eL[wave][e]);
                ++pos;
            }
        }
    }
}

// ---------------------------------------------------------------------------
__global__ __launch_bounds__(256) void k_wtrans(
    const float* __restrict__ W, u16* __restrict__ WT, int K, int N)
{
    __shared__ float til[32][33];
    int k0 = blockIdx.x * 32, n0 = blockIdx.y * 32, s = blockIdx.z;
    const float* Wb = W + (size_t)s * K * N;
    u16* Tb = WT + (size_t)s * N * K;
    int j = threadIdx.x & 31, i0 = threadIdx.x >> 5;
    #pragma unroll
    for (int it = 0; it < 4; ++it) {
        int i = i0 + it * 8;
        til[i][j] = Wb[(size_t)(k0 + i) * N + n0 + j];
    }
    __syncthreads();
    #pragma unroll
    for (int it = 0; it < 4; ++it) {
        int i = i0 + it * 8;
        Tb[(size_t)(n0 + i) * K + k0 + j] = f2us(til[j][i]);
    }
}

// ---------------------------------------------------------------------------
// Fused GNN: R11 structure (64 rows = 2 subgraphs/block, preloaded weight
// registers, (256,2)) + R13 conflict fixes (edge chunk map cc=q*8+g8,
// bond stride 264). hz: logical chunk cc of row r at phys (cc^(r&7))*16B.
__global__ __launch_bounds__(256, 2) void k_gnn4(
    const int* __restrict__ x_ids, const int* __restrict__ dist,
    const int* __restrict__ nodes, const float* __restrict__ lp,
    const float* __restrict__ atom_emb, const float* __restrict__ dist_emb,
    const float* __restrict__ logp_W, const float* __restrict__ logp_b,
    const u16* __restrict__ perm, const u16* __restrict__ off,
    const float* __restrict__ bond_emb, const float* __restrict__ eps_arr,
    const float* __restrict__ b1a, const float* __restrict__ b2a,
    const u16* __restrict__ W1T, const u16* __restrict__ W2T,
    float* __restrict__ x)
{
    __shared__ __align__(16) unsigned char smem[38912];
    u16*   hz    = (u16*)smem;                        // 32768
    float* bondL = (float*)(smem + 32768);            // 5*264*4 = 5280
    u16*   permL = (u16*)(smem + 38048);              // 128 u16 = 256
    u16*   offL  = (u16*)(smem + 38304);              // 64 u16 = 128
    float* validL= (float*)(smem + 38432);            // 64 f32 = 256
    float* epsL  = (float*)(smem + 38688);            // 4 f32

    int tid = threadIdx.x, lane = tid & 63, wave = tid >> 6;
    int row0 = blockIdx.x * 64;
    int fr = lane & 15, quad = lane >> 4;

    for (int i = tid; i < EDN * BSTR; i += 256) {
        int r = i / BSTR, c = i - r * BSTR;
        bondL[i] = (c < 256) ? bond_emb[r * 256 + c] : 0.f;
    }
    if (tid < 128) permL[tid] = perm[blockIdx.x * 128 + tid];
    if (tid < 64) {
        offL[tid] = off[blockIdx.x * 64 + tid];
        validL[tid] = (nodes[row0 + tid] >= 0) ? 1.0f : 0.0f;
    }
    if (tid < 4) epsL[tid] = eps_arr[tid];

    {   // h init: 4 threads/row, 8 chunks each (64 rows)
        int m = tid & 63, qd = tid >> 6;
        int rg = row0 + m;
        float valid = (nodes[rg] >= 0) ? 1.0f : 0.0f;
        float lpv = finite_or_zero(lp[rg >> 5]);
        int dc = dist[rg]; dc = dc < 0 ? 0 : (dc > MAXD ? MAXD : dc);
        int xid = x_ids[rg];
        #pragma unroll
        for (int k = 0; k < 8; ++k) {
            int cc = qd * 8 + k, c = cc * 8;
            float4 a0 = *reinterpret_cast<const float4*>(atom_emb + xid * 256 + c);
            float4 a1 = *reinterpret_cast<const float4*>(atom_emb + xid * 256 + c + 4);
            float4 d0 = *reinterpret_cast<const float4*>(dist_emb + dc * 256 + c);
            float4 d1 = *reinterpret_cast<const float4*>(dist_emb + dc * 256 + c + 4);
            float4 w0 = *reinterpret_cast<const float4*>(logp_W + c);
            float4 w1 = *reinterpret_cast<const float4*>(logp_W + c + 4);
            float4 p0 = *reinterpret_cast<const float4*>(logp_b + c);
            float4 p1 = *reinterpret_cast<const float4*>(logp_b + c + 4);
            union { bf16x8 v; ushort4 h[2]; } o;
            o.h[0] = (ushort4){
                f2us((a0.x + d0.x + fmaxf(lpv * w0.x + p0.x, 0.f)) * valid),
                f2us((a0.y + d0.y + fmaxf(lpv * w0.y + p0.y, 0.f)) * valid),
                f2us((a0.z + d0.z + fmaxf(lpv * w0.z + p0.z, 0.f)) * valid),
                f2us((a0.w + d0.w + fmaxf(lpv * w0.w + p0.w, 0.f)) * valid) };
            o.h[1] = (ushort4){
                f2us((a1.x + d1.x + fmaxf(lpv * w1.x + p1.x, 0.f)) * valid),
                f2us((a1.y + d1.y + fmaxf(lpv * w1.y + p1.y, 0.f)) * valid),
                f2us((a1.z + d1.z + fmaxf(lpv * w1.z + p1.z, 0.f)) * valid),
                f2us((a1.w + d1.w + fmaxf(lpv * w1.w + p1.w, 0.f)) * valid) };
            *reinterpret_cast<bf16x8*>(hz + m * 256 + ((cc ^ (m & 7)) * 8)) = o.v;
        }
    }
    __syncthreads();

    int rl = tid >> 3, g8 = tid & 7;
    for (int l = 0; l < LLAY; ++l) {
        float ep1 = 1.0f + epsL[l];
        for (int p = 0; p < 2; ++p) {
            int row = p * 32 + rl;
            int e0 = offL[p * 32 + rl];
            int e1 = (rl < 31) ? offL[p * 32 + rl + 1] : 64;
            float a[32];
            #pragma unroll
            for (int q = 0; q < 32; ++q) a[q] = 0.f;
            for (int j = e0; j < e1; ++j) {
                int ent = permL[p * 64 + j];
                int sl = p * 32 + (ent >> 3);
                int be = ent & 7;
                #pragma unroll
                for (int q = 0; q < 4; ++q) {
                    int cc = q * 8 + g8;
                    union { bf16x8 v; u16 s[8]; } hv;
                    hv.v = *reinterpret_cast<const bf16x8*>(
                        hz + sl * 256 + ((cc ^ (sl & 7)) * 8));
                    const float* bp = bondL + be * BSTR + cc * 8;
                    float4 bo0 = *reinterpret_cast<const float4*>(bp);
                    float4 bo1 = *reinterpret_cast<const float4*>(bp + 4);
                    a[q*8+0] += fmaxf(us2f(hv.s[0]) + bo0.x, 0.f);
                    a[q*8+1] += fmaxf(us2f(hv.s[1]) + bo0.y, 0.f);
                    a[q*8+2] += fmaxf(us2f(hv.s[2]) + bo0.z, 0.f);
                    a[q*8+3] += fmaxf(us2f(hv.s[3]) + bo0.w, 0.f);
                    a[q*8+4] += fmaxf(us2f(hv.s[4]) + bo1.x, 0.f);
                    a[q*8+5] += fmaxf(us2f(hv.s[5]) + bo1.y, 0.f);
                    a[q*8+6] += fmaxf(us2f(hv.s[6]) + bo1.z, 0.f);
                    a[q*8+7] += fmaxf(us2f(hv.s[7]) + bo1.w, 0.f);
                }
            }
            __syncthreads();
            #pragma unroll
            for (int q = 0; q < 4; ++q) {
                int cc = q * 8 + g8;
                u16* ptr = hz + row * 256 + ((cc ^ (row & 7)) * 8);
                union { bf16x8 v; u16 s[8]; } hv, ov;
                hv.v = *reinterpret_cast<const bf16x8*>(ptr);
                #pragma unroll
                for (int k = 0; k < 8; ++k)
                    ov.s[k] = f2us(ep1 * us2f(hv.s[k]) + a[q * 8 + k]);
                *reinterpret_cast<bf16x8*>(ptr) = ov.v;
            }
        }
        __syncthreads();

        const u16* W1 = W1T + l * 65536;
        const float* b1 = b1a + l * 256;
        bf16x8 wf[4][8];
        #pragma unroll
        for (int i = 0; i < 4; ++i)
            #pragma unroll
            for (int kc = 0; kc < 8; ++kc)
                wf[i][kc] = *reinterpret_cast<const bf16x8*>(
                    W1 + (size_t)(wave * 64 + i * 16 + fr) * 256 + kc * 32 + quad * 8);
        f32x4 acc[4][4];
        #pragma unroll
        for (int i = 0; i < 4; ++i)
            #pragma unroll
            for (int j = 0; j < 4; ++j) acc[i][j] = (f32x4){0.f, 0.f, 0.f, 0.f};
        #pragma unroll
        for (int kc = 0; kc < 8; ++kc) {
            bf16x8 bfv[4];
            #pragma unroll
            for (int j = 0; j < 4; ++j) {
                int m = j * 16 + fr;
                bfv[j] = *reinterpret_cast<const bf16x8*>(hz + m * 256 + (((kc * 4 + quad) ^ (m & 7)) * 8));
            }
            #pragma unroll
            for (int i = 0; i < 4; ++i)
                #pragma unroll
                for (int j = 0; j < 4; ++j)
                    acc[i][j] = __builtin_amdgcn_mfma_f32_16x16x32_bf16(wf[i][kc], bfv[j], acc[i][j], 0, 0, 0);
        }
        __syncthreads();
        #pragma unroll
        for (int i = 0; i < 4; ++i) {
            int n1b = wave * 64 + i * 16 + quad * 4;
            float4 bb = *reinterpret_cast<const float4*>(b1 + n1b);
            #pragma unroll
            for (int j = 0; j < 4; ++j) {
                int m = j * 16 + fr;
                ushort4 o = { f2us(fmaxf(acc[i][j][0] + bb.x, 0.f)),
                              f2us(fmaxf(acc[i][j][1] + bb.y, 0.f)),
                              f2us(fmaxf(acc[i][j][2] + bb.z, 0.f)),
                              f2us(fmaxf(acc[i][j][3] + bb.w, 0.f)) };
                *reinterpret_cast<ushort4*>(hz + m * 256 + (((n1b >> 3) ^ (m & 7)) * 8) + (n1b & 7)) = o;
            }
        }
        __syncthreads();

        const u16* W2 = W2T + l * 65536;
        const float* b2 = b2a + l * 256;
        #pragma unroll
        for (int i = 0; i < 4; ++i)
            #pragma unroll
            for (int kc = 0; kc < 8; ++kc)
                wf[i][kc] = *reinterpret_cast<const bf16x8*>(
                    W2 + (size_t)(wave * 64 + i * 16 + fr) * 256 + kc * 32 + quad * 8);
        #pragma unroll
        for (int i = 0; i < 4; ++i)
            #pragma unroll
            for (int j = 0; j < 4; ++j) acc[i][j] = (f32x4){0.f, 0.f, 0.f, 0.f};
        #pragma unroll
        for (int kc = 0; kc < 8; ++kc) {
            bf16x8 bfv[4];
            #pragma unroll
            for (int j = 0; j < 4; ++j) {
                int m = j * 16 + fr;
                bfv[j] = *reinterpret_cast<const bf16x8*>(hz + m * 256 + (((kc * 4 + quad) ^ (m & 7)) * 8));
            }
            #pragma unroll
            for (int i = 0; i < 4; ++i)
                #pragma unroll
                for (int j = 0; j < 4; ++j)
                    acc[i][j] = __builtin_amdgcn_mfma_f32_16x16x32_bf16(wf[i][kc], bfv[j], acc[i][j], 0, 0, 0);
        }
        __syncthreads();

        if (l < LLAY - 1) {
            #pragma unroll
            for (int i = 0; i < 4; ++i) {
                int n2b = wave * 64 + i * 16 + quad * 4;
                float4 bb = *reinterpret_cast<const float4*>(b2 + n2b);
                #pragma unroll
                for (int j = 0; j < 4; ++j) {
                    int m = j * 16 + fr;
                    float vm = validL[m];
                    ushort4 o = { f2us((acc[i][j][0] + bb.x) * vm),
                                  f2us((acc[i][j][1] + bb.y) * vm),
                                  f2us((acc[i][j][2] + bb.z) * vm),
                                  f2us((acc[i][j][3] + bb.w) * vm) };
                    *reinterpret_cast<ushort4*>(hz + m * 256 + (((n2b >> 3) ^ (m & 7)) * 8) + (n2b & 7)) = o;
                }
            }
            __syncthreads();
        } else {
            if (fr == 0) {
                #pragma unroll
                for (int i = 0; i < 4; ++i) {
                    int n2b = wave * 64 + i * 16 + quad * 4;
                    float4 bb = *reinterpret_cast<const float4*>(b2 + n2b);
                    #pragma unroll
                    for (int jj = 0; jj < 2; ++jj) {
                        int j = jj * 2, m = j * 16;   // m = 0, 32
                        float vm = validL[m];
                        float4 o = { (acc[i][j][0] + bb.x) * vm,
                                     (acc[i][j][1] + bb.y) * vm,
                                     (acc[i][j][2] + bb.z) * vm,
                                     (acc[i][j][3] + bb.w) * vm };
                        *reinterpret_cast<float4*>(
                            x + (size_t)(blockIdx.x * 2 + (m >> 5)) * 256 + n2b) = o;
                    }
                }
            }
        }
    }
}

// ---------------------------------------------------------------------------
__global__ __launch_bounds__(1024) void k_bias(
    const int* __restrict__ nodes, const float* __restrict__ lp,
    const float* __restrict__ ovl_emb, const float* __restrict__ alpha_p,
    float* __restrict__ bias)
{
    int b = blockIdx.x, tid = threadIdx.x;
    __shared__ int nd[32][32];
    __shared__ unsigned int bmv[32][17];
    __shared__ float lpc[32];
    __shared__ float emb[16];
    nd[tid >> 5][tid & 31] = nodes[b * 1024 + tid];
    if (tid < 512) bmv[tid >> 4][tid & 15] = 0u;
    if (tid < 32) {
        float l = finite_or_zero(lp[b * 32 + tid]);
        l = l < -30.f ? -30.f : (l > 0.f ? 0.f : l);
        lpc[tid] = l;
    }
    if (tid >= 64 && tid < 64 + KMAXC + 1) emb[tid - 64] = ovl_emb[tid - 64];
    __syncthreads();
    int own = nd[tid >> 5][tid & 31];
    if (own >= 0) atomicOr(&bmv[tid >> 5][own >> 5], 1u << (own & 31));
    __syncthreads();
    int i = tid >> 5, j = tid & 31;
    float alpha = alpha_p[0];
    int cnt = 0;
    #pragma unroll
    for (int k = 0; k < 32; ++k) {
        int nk = nd[i][k];
        if (nk >= 0) cnt += (int)((bmv[j][nk >> 5] >> (nk & 31)) & 1u);
    }
    bias[b * 1024 + tid] = emb[cnt > KMAXC ? KMAXC : cnt] - alpha * lpc[j];
}

// ---------------------------------------------------------------------------
// LN(X) @ BT^T, 32x64 tile, K=256. Full B panel LDS-resident (32 KB, swizzled)
// -> barrier-free kc loop (one barrier after staging).
__global__ __launch_bounds__(256) void k_gemmA_ln(
    const float* __restrict__ X, const u16* __restrict__ BT,
    const float* __restrict__ ln_g, const float* __restrict__ ln_b,
    const float* __restrict__ bias, u16* __restrict__ C,
    int N, int act)
{
    __shared__ __align__(16) u16 As[32 * 256];     // 16 KB
    __shared__ __align__(16) u16 Bs[64 * 256];     // 32 KB
    int tid = threadIdx.x, lane = tid & 63, wave = tid >> 6;
    int wm = wave >> 1, wn = wave & 1;
    int bm = blockIdx.y * 32, bn = blockIdx.x * 64;
    int fr = lane & 15, quad = lane >> 4;

    // stage full B panel: 32 segments of 1 KB (2 rows each), swizzled
    #pragma unroll
    for (int t = 0; t < 8; ++t) {
        int v = t * 4 + wave;
        int r = v * 2 + (lane >> 5);
        int p = lane & 31;
        int cc = p ^ (r & 7);
        gll16(BT + (size_t)(bn + r) * 256 + cc * 8, Bs + v * 512);
    }
    // LN -> As (swizzled)
    #pragma unroll
    for (int rr = 0; rr < 8; ++rr) {
        int r = wave * 8 + rr;
        float4 xv = *reinterpret_cast<const float4*>(X + (size_t)(bm + r) * 256 + lane * 4);
        float s = xv.x + xv.y + xv.z + xv.w;
        #pragma unroll
        for (int o2 = 32; o2 > 0; o2 >>= 1) s += __shfl_xor(s, o2);
        float mu = s * (1.0f / 256.0f);
        float d0 = xv.x - mu, d1 = xv.y - mu, d2 = xv.z - mu, d3 = xv.w - mu;
        float sq = d0 * d0 + d1 * d1 + d2 * d2 + d3 * d3;
        #pragma unroll
        for (int o2 = 32; o2 > 0; o2 >>= 1) sq += __shfl_xor(sq, o2);
        float rs = rsqrtf(sq * (1.0f / 256.0f) + 1e-5f);
        int c = lane * 4;
        float4 gv = *reinterpret_cast<const float4*>(ln_g + c);
        float4 bv = *reinterpret_cast<const float4*>(ln_b + c);
        ushort4 o = { f2us(d0 * rs * gv.x + bv.x), f2us(d1 * rs * gv.y + bv.y),
                      f2us(d2 * rs * gv.z + bv.z), f2us(d3 * rs * gv.w + bv.w) };
        *reinterpret_cast<ushort4*>(As + r * 256 + (((lane >> 1) ^ (r & 7)) * 8) + (lane & 1) * 4) = o;
    }
    __syncthreads();

    f32x4 acc[2];
    acc[0] = (f32x4){0,0,0,0}; acc[1] = (f32x4){0,0,0,0};
    #pragma unroll
    for (int kc = 0; kc < 8; ++kc) {
        int am = wm * 16 + fr;
        bf16x8 af = *reinterpret_cast<const bf16x8*>(
            As + am * 256 + (((kc * 4 + quad) ^ (am & 7)) * 8));
        bf16x8 bfr[2];
        #pragma unroll
        for (int j = 0; j < 2; ++j) {
            int br = wn * 32 + j * 16 + fr;
            bfr[j] = *reinterpret_cast<const bf16x8*>(
                Bs + br * 256 + (((kc * 4 + quad) ^ (br & 7)) * 8));
        }
        acc[0] = __builtin_amdgcn_mfma_f32_16x16x32_bf16(af, bfr[0], acc[0], 0, 0, 0);
        acc[1] = __builtin_amdgcn_mfma_f32_16x16x32_bf16(af, bfr[1], acc[1], 0, 0, 0);
    }
    int crow0 = bm + wm * 16 + quad * 4;
    int ccol0 = bn + wn * 32 + fr;
    #pragma unroll
    for (int r = 0; r < 4; ++r) {
        int m = crow0 + r;
        #pragma unroll
        for (int j = 0; j < 2; ++j) {
            int n = ccol0 + j * 16;
            float v = acc[j][r];
            if (bias) v += bias[n];
            if (act == 2) v = 0.5f * v * (1.0f + erff(v * 0.70710678118654752f));
            C[(size_t)m * N + n] = f2us(v);
        }
    }
}

// ---------------------------------------------------------------------------
// bf16 GEMM 32x64 tile, paneled K (256 per panel), barrier-free inner loop.
// f32 out + bias + resid.
__global__ __launch_bounds__(256) void k_gemmB(
    const u16* __restrict__ A, const u16* __restrict__ BT,
    const float* __restrict__ bias, float* __restrict__ Cout,
    const float* __restrict__ resid, int M, int K, int N)
{
    __shared__ __align__(16) u16 As[32 * 256];     // 16 KB
    __shared__ __align__(16) u16 Bs[64 * 256];     // 32 KB
    int tid = threadIdx.x, lane = tid & 63, wave = tid >> 6;
    int wm = wave >> 1, wn = wave & 1;
    int bm = blockIdx.y * 32, bn = blockIdx.x * 64;
    int fr = lane & 15, quad = lane >> 4;
    int npan = K >> 8;

    f32x4 acc[2];
    acc[0] = (f32x4){0,0,0,0}; acc[1] = (f32x4){0,0,0,0};
    for (int pan = 0; pan < npan; ++pan) {
        if (pan) __syncthreads();   // prior panel reads complete
        int kbase = pan * 256;
        // A panel: 16 segments (2 rows each of 32 chunks)
        #pragma unroll
        for (int t = 0; t < 4; ++t) {
            int v = t * 4 + wave;
            int r = v * 2 + (lane >> 5);
            int p = lane & 31;
            int cc = p ^ (r & 7);
            gll16(A + (size_t)(bm + r) * K + kbase + cc * 8, As + v * 512);
        }
        // B panel: 32 segments
        #pragma unroll
        for (int t = 0; t < 8; ++t) {
            int v = t * 4 + wave;
            int r = v * 2 + (lane >> 5);
            int p = lane & 31;
            int cc = p ^ (r & 7);
            gll16(BT + (size_t)(bn + r) * K + kbase + cc * 8, Bs + v * 512);
        }
        __syncthreads();
        #pragma unroll
        for (int kc = 0; kc < 8; ++kc) {
            int am = wm * 16 + fr;
            bf16x8 af = *reinterpret_cast<const bf16x8*>(
                As + am * 256 + (((kc * 4 + quad) ^ (am & 7)) * 8));
            bf16x8 bfr[2];
            #pragma unroll
            for (int j = 0; j < 2; ++j) {
                int br = wn * 32 + j * 16 + fr;
                bfr[j] = *reinterpret_cast<const bf16x8*>(
                    Bs + br * 256 + (((kc * 4 + quad) ^ (br & 7)) * 8));
            }
            acc[0] = __builtin_amdgcn_mfma_f32_16x16x32_bf16(af, bfr[0], acc[0], 0, 0, 0);
            acc[1] = __builtin_amdgcn_mfma_f32_16x16x32_bf16(af, bfr[1], acc[1], 0, 0, 0);
        }
    }
    int crow0 = bm + wm * 16 + quad * 4;
    int ccol0 = bn + wn * 32 + fr;
    #pragma unroll
    for (int r = 0; r < 4; ++r) {
        int m = crow0 + r;
        #pragma unroll
        for (int j = 0; j < 2; ++j) {
            int n = ccol0 + j * 16;
            Cout[(size_t)m * N + n] = acc[j][r] + bias[n] + resid[(size_t)m * N + n];
        }
    }
}

// ---------------------------------------------------------------------------
// Attention per (batch, head) — verified R8 body.
__global__ __launch_bounds__(256) void k_attn(
    const u16* __restrict__ qkv, const float* __restrict__ bias, u16* __restrict__ o)
{
    int b = blockIdx.x >> 2, hh = blockIdx.x & 3;
    __shared__ float qs[32][65], ks[32][65], vs[32][65];
    __shared__ float sc[32][33];
    int tid = threadIdx.x;
    #pragma unroll
    for (int u = 0; u < 8; ++u) {
        int idx = tid + u * 256;
        int i = idx >> 6, d = idx & 63;
        size_t base = (size_t)(b * 32 + i) * 768;
        qs[i][d] = us2f(qkv[base + hh * 64 + d]);
        ks[i][d] = us2f(qkv[base + 256 + hh * 64 + d]);
        vs[i][d] = us2f(qkv[base + 512 + hh * 64 + d]);
    }
    __syncthreads();
    #pragma unroll
    for (int u = 0; u < 4; ++u) {
        int p = tid + u * 256;
        int i = p >> 5, j = p & 31;
        float s = 0.f;
        #pragma unroll
        for (int d = 0; d < 64; ++d) s += qs[i][d] * ks[j][d];
        sc[i][j] = s * 0.125f + bias[b * 1024 + i * 32 + j];
    }
    __syncthreads();
    if (tid < 32) {
        int i = tid;
        float m = -1e30f;
        for (int j = 0; j < 32; ++j) m = fmaxf(m, sc[i][j]);
        float sum = 0.f;
        for (int j = 0; j < 32; ++j) { float e = expf(sc[i][j] - m); sc[i][j] = e; sum += e; }
        float inv = 1.0f / sum;
        for (int j = 0; j < 32; ++j) sc[i][j] *= inv;
    }
    __syncthreads();
    #pragma unroll
    for (int u = 0; u < 8; ++u) {
        int idx = tid + u * 256;
        int i = idx >> 6, d = idx & 63;
        float a = 0.f;
        #pragma unroll
        for (int j = 0; j < 32; ++j) a += sc[i][j] * vs[j][d];
        o[(size_t)(b * 32 + i) * 256 + hh * 64 + d] = f2us(a);
    }
}

// ---------------------------------------------------------------------------
// Final LN + softmax(-lp_c)-weighted sum (verified R11 body).
__global__ __launch_bounds__(256) void k_fin(
    const float* __restrict__ x, const float* __restrict__ lp,
    const float* __restrict__ lnout_g, const float* __restrict__ lnout_b,
    float* __restrict__ out)
{
    __shared__ __align__(16) float xlnf[32 * 260];
    __shared__ float wfin[32];
    int tid = threadIdx.x, lane = tid & 63, wave = tid >> 6;
    int b = blockIdx.x;
    #pragma unroll
    for (int rr = 0; rr < 8; ++rr) {
        int row = wave * 8 + rr;
        float4 xv = *reinterpret_cast<const float4*>(x + (size_t)(b * 32 + row) * 256 + lane * 4);
        float s = xv.x + xv.y + xv.z + xv.w;
        #pragma unroll
        for (int o2 = 32; o2 > 0; o2 >>= 1) s += __shfl_xor(s, o2);
        float mu = s * (1.0f / 256.0f);
        float d0 = xv.x - mu, d1 = xv.y - mu, d2 = xv.z - mu, d3 = xv.w - mu;
        float sq = d0 * d0 + d1 * d1 + d2 * d2 + d3 * d3;
        #pragma unroll
        for (int o2 = 32; o2 > 0; o2 >>= 1) sq += __shfl_xor(sq, o2);
        float rs = rsqrtf(sq * (1.0f / 256.0f) + 1e-5f);
        int c = lane * 4;
        float4 gv = *reinterpret_cast<const float4*>(lnout_g + c);
        float4 bv = *reinterpret_cast<const float4*>(lnout_b + c);
        float4 o = { d0 * rs * gv.x + bv.x, d1 * rs * gv.y + bv.y,
                     d2 * rs * gv.z + bv.z, d3 * rs * gv.w + bv.w };
        *reinterpret_cast<float4*>(xlnf + row * 260 + c) = o;
    }
    __syncthreads();
    if (tid == 0) {
        float l2[32];
        float m = -1e30f;
        for (int i = 0; i < 32; ++i) {
            float l = finite_or_zero(lp[b * 32 + i]);
            l = l < -30.f ? -30.f : (l > 0.f ? 0.f : l);
            l2[i] = -l;
            m = fmaxf(m, -l);
        }
        float s = 0.f;
        for (int i = 0; i < 32; ++i) { float e = expf(l2[i] - m); wfin[i] = e; s += e; }
        float inv = 1.0f / s;
        for (int i = 0; i < 32; ++i) wfin[i] *= inv;
    }
    __syncthreads();
    float a = 0.f;
    for (int i = 0; i < 32; ++i) a += wfin[i] * xlnf[i * 260 + tid];
    out[(size_t)b * 256 + tid] = a;
}

// ---------------------------------------------------------------------------
extern "C" void kernel_launch(void* const* d_in, const int* in_sizes, int n_in,
                              void* d_out, int out_size, void* d_ws, size_t ws_size,
                              hipStream_t stream)
{
    const int*   x_ids    = (const int*)d_in[0];
    const int*   edge_ids = (const int*)d_in[1];
    const int*   srcp     = (const int*)d_in[2];
    const int*   dstp     = (const int*)d_in[3];
    const int*   nodes    = (const int*)d_in[4];
    const int*   dist     = (const int*)d_in[5];
    const float* lp       = (const float*)d_in[6];
    const float* atom_emb = (const float*)d_in[7];
    const float* bond_emb = (const float*)d_in[8];
    const float* dist_emb = (const float*)d_in[9];
    const float* logp_W   = (const float*)d_in[10];
    const float* logp_b   = (const float*)d_in[11];
    const float* gnn_eps  = (const float*)d_in[12];
    const float* gnn_W1   = (const float*)d_in[13];
    const float* gnn_b1   = (const float*)d_in[14];
    const float* gnn_W2   = (const float*)d_in[15];
    const float* gnn_b2   = (const float*)d_in[16];
    const float* ln1_g    = (const float*)d_in[17];
    const float* ln1_b    = (const float*)d_in[18];
    const float* qkv_W    = (const float*)d_in[19];
    const float* out_W    = (const float*)d_in[20];
    const float* out_b    = (const float*)d_in[21];
    const float* ln2_g    = (const float*)d_in[22];
    const float* ln2_b    = (const float*)d_in[23];
    const float* f1_W     = (const float*)d_in[24];
    const float* f1_b     = (const float*)d_in[25];
    const float* f2_W     = (const float*)d_in[26];
    const float* f2_b     = (const float*)d_in[27];
    const float* lnout_g  = (const float*)d_in[28];
    const float* lnout_b  = (const float*)d_in[29];
    const float* ovl_emb  = (const float*)d_in[30];
    const float* alpha    = (const float*)d_in[31];

    char* ws = (char*)d_ws;
    u16*   gW1T  = (u16*)(ws + 100663296ull);
    u16*   gW2T  = (u16*)(ws + 100663296ull + 524288ull);
    u16*   permW = (u16*)(ws + 100663296ull + 1048576ull);
    u16*   offW  = (u16*)(ws + 100663296ull + 1310720ull);
    u16*   qkvT  = (u16*)(ws + 33554432ull);
    u16*   outT  = (u16*)(ws + 33554432ull + 1572864ull);
    u16*   f1T   = (u16*)(ws + 33554432ull + 2097152ull);
    u16*   f2T   = (u16*)(ws + 33554432ull + 4194304ull);
    u16*   ob    = (u16*)(ws + 33554432ull + 6291456ull);
    float* biasb = (float*)(ws + 33554432ull + 7340032ull);
    u16*   qkvb  = (u16*)(ws + 33554432ull + 7602176ull);
    u16*   ffh   = (u16*)(ws + 33554432ull + 10747904ull);
    float* x     = (float*)(ws + 67108864ull);

    k_csr<<<SSUB / 4, 256, 0, stream>>>(srcp, dstp, edge_ids, permW, offW);
    k_wtrans<<<dim3(8, 8, 4), 256, 0, stream>>>(gnn_W1, gW1T, 256, 256);
    k_wtrans<<<dim3(8, 8, 4), 256, 0, stream>>>(gnn_W2, gW2T, 256, 256);
    k_gnn4<<<NNODE / 64, 256, 0, stream>>>(
        x_ids, dist, nodes, lp, atom_emb, dist_emb, logp_W, logp_b,
        permW, offW, bond_emb, gnn_eps, gnn_b1, gnn_b2, gW1T, gW2T, x);
    k_wtrans<<<dim3(8, 24, 4), 256, 0, stream>>>(qkv_W, qkvT, 256, 768);
    k_wtrans<<<dim3(8, 8, 4), 256, 0, stream>>>(out_W, outT, 256, 256);
    k_wtrans<<<dim3(8, 32, 4), 256, 0, stream>>>(f1_W, f1T, 256, 1024);
    k_wtrans<<<dim3(32, 8, 4), 256, 0, stream>>>(f2_W, f2T, 1024, 256);
    k_bias<<<BATCH, 1024, 0, stream>>>(nodes, lp, ovl_emb, alpha, biasb);
    for (int t = 0; t < TLAY; ++t) {
        k_gemmA_ln<<<dim3(12, 64), 256, 0, stream>>>(
            x, qkvT + (size_t)t * 768 * 256, ln1_g + t * 256, ln1_b + t * 256,
            nullptr, qkvb, 768, 0);
        k_attn<<<BATCH * NHEAD, 256, 0, stream>>>(qkvb, biasb, ob);
        k_gemmB<<<dim3(4, 64), 256, 0, stream>>>(
            ob, outT + (size_t)t * 65536, out_b + t * 256, x, x, SSUB, 256, 256);
        k_gemmA_ln<<<dim3(16, 64), 256, 0, stream>>>(
            x, f1T + (size_t)t * 1024 * 256, ln2_g + t * 256, ln2_b + t * 256,
            f1_b + t * 1024, ffh, 1024, 2);
        k_gemmB<<<dim3(4, 64), 256, 0, stream>>>(
            ffh, f2T + (size_t)t * 256 * 1024, f2_b + t * 256, x, x, SSUB, 1024, 256);
    }
    k_fin<<<BATCH, 256, 0, stream>>>(x, lp, lnout_g, lnout_b, (float*)d_out);
}

// Round 15
// 523.059 us; speedup vs baseline: 1.1738x; 1.0047x over previous
//
#include <hip/hip_runtime.h>
#include <hip/hip_bf16.h>
#include <math.h>

#define HDIM   256
#define NHEAD  4
#define LLAY   4
#define TLAY   4
#define KMAXC  10
#define MAXD   32
#define BATCH  64
#define MSUB   32
#define KNODE  32
#define SSUB   2048
#define NNODE  65536
#define NEDGE  131072
#define EPSPER 64
#define EDN    5
#define BSTR   264   // bondL padded stride (floats)

typedef unsigned short u16;
typedef __attribute__((ext_vector_type(8))) short bf16x8;
typedef __attribute__((ext_vector_type(4))) float f32x4;

__device__ __forceinline__ float us2f(u16 u) {
    union { unsigned int i; float f; } x; x.i = ((unsigned int)u) << 16; return x.f;
}
__device__ __forceinline__ u16 f2us(float v) {
    union { float f; unsigned int i; } x; x.f = v;
    unsigned int u = x.i;
    u += 0x7fffu + ((u >> 16) & 1u);   // RNE
    return (u16)(u >> 16);
}
__device__ __forceinline__ float finite_or_zero(float v) {
    return (v == v && fabsf(v) <= 3.0e38f) ? v : 0.0f;
}
__device__ __forceinline__ void gll16(const u16* g, u16* l) {
    __builtin_amdgcn_global_load_lds(
        (const __attribute__((address_space(1))) unsigned int*)g,
        (__attribute__((address_space(3))) unsigned int*)l, 16, 0, 0);
}

// ---------------------------------------------------------------------------
__global__ __launch_bounds__(256) void k_csr(
    const int* __restrict__ src, const int* __restrict__ dst,
    const int* __restrict__ eid, u16* __restrict__ perm, u16* __restrict__ off)
{
    __shared__ int sL[4][64], dL[4][64], eL[4][64];
    int wave = threadIdx.x >> 6, lane = threadIdx.x & 63;
    int sgi = blockIdx.x * 4 + wave;
    sL[wave][lane] = src[sgi * 64 + lane] - sgi * KNODE;
    dL[wave][lane] = dst[sgi * 64 + lane] - sgi * KNODE;
    eL[wave][lane] = eid[sgi * 64 + lane];
    __syncthreads();
    if (lane < 32) {
        int cnt = 0;
        for (int e = 0; e < 64; ++e) cnt += (dL[wave][e] == lane) ? 1 : 0;
        int incl = cnt;
        #pragma unroll
        for (int d = 1; d < 32; d <<= 1) {
            int v = __shfl_up(incl, d, 64);
            if (lane >= d) incl += v;
        }
        int start = incl - cnt;
        off[sgi * 32 + lane] = (u16)start;
        int pos = start;
        for (int e = 0; e < 64; ++e) {
            if (dL[wave][e] == lane) {
                perm[sgi * 64 + pos] = (u16)((sL[wave][e] << 3) | eL[wave][e]);
                ++pos;
            }
        }
    }
}

// ---------------------------------------------------------------------------
__global__ __launch_bounds__(256) void k_wtrans(
    const float* __restrict__ W, u16* __restrict__ WT, int K, int N)
{
    __shared__ float til[32][33];
    int k0 = blockIdx.x * 32, n0 = blockIdx.y * 32, s = blockIdx.z;
    const float* Wb = W + (size_t)s * K * N;
    u16* Tb = WT + (size_t)s * N * K;
    int j = threadIdx.x & 31, i0 = threadIdx.x >> 5;
    #pragma unroll
    for (int it = 0; it < 4; ++it) {
        int i = i0 + it * 8;
        til[i][j] = Wb[(size_t)(k0 + i) * N + n0 + j];
    }
    __syncthreads();
    #pragma unroll
    for (int it = 0; it < 4; ++it) {
        int i = i0 + it * 8;
        Tb[(size_t)(n0 + i) * K + k0 + j] = f2us(til[j][i]);
    }
}

// ---------------------------------------------------------------------------
// Fused GNN (R14 verified: R11 structure + R13 conflict fixes). UNCHANGED.
__global__ __launch_bounds__(256, 2) void k_gnn4(
    const int* __restrict__ x_ids, const int* __restrict__ dist,
    const int* __restrict__ nodes, const float* __restrict__ lp,
    const float* __restrict__ atom_emb, const float* __restrict__ dist_emb,
    const float* __restrict__ logp_W, const float* __restrict__ logp_b,
    const u16* __restrict__ perm, const u16* __restrict__ off,
    const float* __restrict__ bond_emb, const float* __restrict__ eps_arr,
    const float* __restrict__ b1a, const float* __restrict__ b2a,
    const u16* __restrict__ W1T, const u16* __restrict__ W2T,
    float* __restrict__ x)
{
    __shared__ __align__(16) unsigned char smem[38912];
    u16*   hz    = (u16*)smem;
    float* bondL = (float*)(smem + 32768);
    u16*   permL = (u16*)(smem + 38048);
    u16*   offL  = (u16*)(smem + 38304);
    float* validL= (float*)(smem + 38432);
    float* epsL  = (float*)(smem + 38688);

    int tid = threadIdx.x, lane = tid & 63, wave = tid >> 6;
    int row0 = blockIdx.x * 64;
    int fr = lane & 15, quad = lane >> 4;

    for (int i = tid; i < EDN * BSTR; i += 256) {
        int r = i / BSTR, c = i - r * BSTR;
        bondL[i] = (c < 256) ? bond_emb[r * 256 + c] : 0.f;
    }
    if (tid < 128) permL[tid] = perm[blockIdx.x * 128 + tid];
    if (tid < 64) {
        offL[tid] = off[blockIdx.x * 64 + tid];
        validL[tid] = (nodes[row0 + tid] >= 0) ? 1.0f : 0.0f;
    }
    if (tid < 4) epsL[tid] = eps_arr[tid];

    {
        int m = tid & 63, qd = tid >> 6;
        int rg = row0 + m;
        float valid = (nodes[rg] >= 0) ? 1.0f : 0.0f;
        float lpv = finite_or_zero(lp[rg >> 5]);
        int dc = dist[rg]; dc = dc < 0 ? 0 : (dc > MAXD ? MAXD : dc);
        int xid = x_ids[rg];
        #pragma unroll
        for (int k = 0; k < 8; ++k) {
            int cc = qd * 8 + k, c = cc * 8;
            float4 a0 = *reinterpret_cast<const float4*>(atom_emb + xid * 256 + c);
            float4 a1 = *reinterpret_cast<const float4*>(atom_emb + xid * 256 + c + 4);
            float4 d0 = *reinterpret_cast<const float4*>(dist_emb + dc * 256 + c);
            float4 d1 = *reinterpret_cast<const float4*>(dist_emb + dc * 256 + c + 4);
            float4 w0 = *reinterpret_cast<const float4*>(logp_W + c);
            float4 w1 = *reinterpret_cast<const float4*>(logp_W + c + 4);
            float4 p0 = *reinterpret_cast<const float4*>(logp_b + c);
            float4 p1 = *reinterpret_cast<const float4*>(logp_b + c + 4);
            union { bf16x8 v; ushort4 h[2]; } o;
            o.h[0] = (ushort4){
                f2us((a0.x + d0.x + fmaxf(lpv * w0.x + p0.x, 0.f)) * valid),
                f2us((a0.y + d0.y + fmaxf(lpv * w0.y + p0.y, 0.f)) * valid),
                f2us((a0.z + d0.z + fmaxf(lpv * w0.z + p0.z, 0.f)) * valid),
                f2us((a0.w + d0.w + fmaxf(lpv * w0.w + p0.w, 0.f)) * valid) };
            o.h[1] = (ushort4){
                f2us((a1.x + d1.x + fmaxf(lpv * w1.x + p1.x, 0.f)) * valid),
                f2us((a1.y + d1.y + fmaxf(lpv * w1.y + p1.y, 0.f)) * valid),
                f2us((a1.z + d1.z + fmaxf(lpv * w1.z + p1.z, 0.f)) * valid),
                f2us((a1.w + d1.w + fmaxf(lpv * w1.w + p1.w, 0.f)) * valid) };
            *reinterpret_cast<bf16x8*>(hz + m * 256 + ((cc ^ (m & 7)) * 8)) = o.v;
        }
    }
    __syncthreads();

    int rl = tid >> 3, g8 = tid & 7;
    for (int l = 0; l < LLAY; ++l) {
        float ep1 = 1.0f + epsL[l];
        for (int p = 0; p < 2; ++p) {
            int row = p * 32 + rl;
            int e0 = offL[p * 32 + rl];
            int e1 = (rl < 31) ? offL[p * 32 + rl + 1] : 64;
            float a[32];
            #pragma unroll
            for (int q = 0; q < 32; ++q) a[q] = 0.f;
            for (int j = e0; j < e1; ++j) {
                int ent = permL[p * 64 + j];
                int sl = p * 32 + (ent >> 3);
                int be = ent & 7;
                #pragma unroll
                for (int q = 0; q < 4; ++q) {
                    int cc = q * 8 + g8;
                    union { bf16x8 v; u16 s[8]; } hv;
                    hv.v = *reinterpret_cast<const bf16x8*>(
                        hz + sl * 256 + ((cc ^ (sl & 7)) * 8));
                    const float* bp = bondL + be * BSTR + cc * 8;
                    float4 bo0 = *reinterpret_cast<const float4*>(bp);
                    float4 bo1 = *reinterpret_cast<const float4*>(bp + 4);
                    a[q*8+0] += fmaxf(us2f(hv.s[0]) + bo0.x, 0.f);
                    a[q*8+1] += fmaxf(us2f(hv.s[1]) + bo0.y, 0.f);
                    a[q*8+2] += fmaxf(us2f(hv.s[2]) + bo0.z, 0.f);
                    a[q*8+3] += fmaxf(us2f(hv.s[3]) + bo0.w, 0.f);
                    a[q*8+4] += fmaxf(us2f(hv.s[4]) + bo1.x, 0.f);
                    a[q*8+5] += fmaxf(us2f(hv.s[5]) + bo1.y, 0.f);
                    a[q*8+6] += fmaxf(us2f(hv.s[6]) + bo1.z, 0.f);
                    a[q*8+7] += fmaxf(us2f(hv.s[7]) + bo1.w, 0.f);
                }
            }
            __syncthreads();
            #pragma unroll
            for (int q = 0; q < 4; ++q) {
                int cc = q * 8 + g8;
                u16* ptr = hz + row * 256 + ((cc ^ (row & 7)) * 8);
                union { bf16x8 v; u16 s[8]; } hv, ov;
                hv.v = *reinterpret_cast<const bf16x8*>(ptr);
                #pragma unroll
                for (int k = 0; k < 8; ++k)
                    ov.s[k] = f2us(ep1 * us2f(hv.s[k]) + a[q * 8 + k]);
                *reinterpret_cast<bf16x8*>(ptr) = ov.v;
            }
        }
        __syncthreads();

        const u16* W1 = W1T + l * 65536;
        const float* b1 = b1a + l * 256;
        bf16x8 wf[4][8];
        #pragma unroll
        for (int i = 0; i < 4; ++i)
            #pragma unroll
            for (int kc = 0; kc < 8; ++kc)
                wf[i][kc] = *reinterpret_cast<const bf16x8*>(
                    W1 + (size_t)(wave * 64 + i * 16 + fr) * 256 + kc * 32 + quad * 8);
        f32x4 acc[4][4];
        #pragma unroll
        for (int i = 0; i < 4; ++i)
            #pragma unroll
            for (int j = 0; j < 4; ++j) acc[i][j] = (f32x4){0.f, 0.f, 0.f, 0.f};
        #pragma unroll
        for (int kc = 0; kc < 8; ++kc) {
            bf16x8 bfv[4];
            #pragma unroll
            for (int j = 0; j < 4; ++j) {
                int m = j * 16 + fr;
                bfv[j] = *reinterpret_cast<const bf16x8*>(hz + m * 256 + (((kc * 4 + quad) ^ (m & 7)) * 8));
            }
            #pragma unroll
            for (int i = 0; i < 4; ++i)
                #pragma unroll
                for (int j = 0; j < 4; ++j)
                    acc[i][j] = __builtin_amdgcn_mfma_f32_16x16x32_bf16(wf[i][kc], bfv[j], acc[i][j], 0, 0, 0);
        }
        __syncthreads();
        #pragma unroll
        for (int i = 0; i < 4; ++i) {
            int n1b = wave * 64 + i * 16 + quad * 4;
            float4 bb = *reinterpret_cast<const float4*>(b1 + n1b);
            #pragma unroll
            for (int j = 0; j < 4; ++j) {
                int m = j * 16 + fr;
                ushort4 o = { f2us(fmaxf(acc[i][j][0] + bb.x, 0.f)),
                              f2us(fmaxf(acc[i][j][1] + bb.y, 0.f)),
                              f2us(fmaxf(acc[i][j][2] + bb.z, 0.f)),
                              f2us(fmaxf(acc[i][j][3] + bb.w, 0.f)) };
                *reinterpret_cast<ushort4*>(hz + m * 256 + (((n1b >> 3) ^ (m & 7)) * 8) + (n1b & 7)) = o;
            }
        }
        __syncthreads();

        const u16* W2 = W2T + l * 65536;
        const float* b2 = b2a + l * 256;
        #pragma unroll
        for (int i = 0; i < 4; ++i)
            #pragma unroll
            for (int kc = 0; kc < 8; ++kc)
                wf[i][kc] = *reinterpret_cast<const bf16x8*>(
                    W2 + (size_t)(wave * 64 + i * 16 + fr) * 256 + kc * 32 + quad * 8);
        #pragma unroll
        for (int i = 0; i < 4; ++i)
            #pragma unroll
            for (int j = 0; j < 4; ++j) acc[i][j] = (f32x4){0.f, 0.f, 0.f, 0.f};
        #pragma unroll
        for (int kc = 0; kc < 8; ++kc) {
            bf16x8 bfv[4];
            #pragma unroll
            for (int j = 0; j < 4; ++j) {
                int m = j * 16 + fr;
                bfv[j] = *reinterpret_cast<const bf16x8*>(hz + m * 256 + (((kc * 4 + quad) ^ (m & 7)) * 8));
            }
            #pragma unroll
            for (int i = 0; i < 4; ++i)
                #pragma unroll
                for (int j = 0; j < 4; ++j)
                    acc[i][j] = __builtin_amdgcn_mfma_f32_16x16x32_bf16(wf[i][kc], bfv[j], acc[i][j], 0, 0, 0);
        }
        __syncthreads();

        if (l < LLAY - 1) {
            #pragma unroll
            for (int i = 0; i < 4; ++i) {
                int n2b = wave * 64 + i * 16 + quad * 4;
                float4 bb = *reinterpret_cast<const float4*>(b2 + n2b);
                #pragma unroll
                for (int j = 0; j < 4; ++j) {
                    int m = j * 16 + fr;
                    float vm = validL[m];
                    ushort4 o = { f2us((acc[i][j][0] + bb.x) * vm),
                                  f2us((acc[i][j][1] + bb.y) * vm),
                                  f2us((acc[i][j][2] + bb.z) * vm),
                                  f2us((acc[i][j][3] + bb.w) * vm) };
                    *reinterpret_cast<ushort4*>(hz + m * 256 + (((n2b >> 3) ^ (m & 7)) * 8) + (n2b & 7)) = o;
                }
            }
            __syncthreads();
        } else {
            if (fr == 0) {
                #pragma unroll
                for (int i = 0; i < 4; ++i) {
                    int n2b = wave * 64 + i * 16 + quad * 4;
                    float4 bb = *reinterpret_cast<const float4*>(b2 + n2b);
                    #pragma unroll
                    for (int jj = 0; jj < 2; ++jj) {
                        int j = jj * 2, m = j * 16;
                        float vm = validL[m];
                        float4 o = { (acc[i][j][0] + bb.x) * vm,
                                     (acc[i][j][1] + bb.y) * vm,
                                     (acc[i][j][2] + bb.z) * vm,
                                     (acc[i][j][3] + bb.w) * vm };
                        *reinterpret_cast<float4*>(
                            x + (size_t)(blockIdx.x * 2 + (m >> 5)) * 256 + n2b) = o;
                    }
                }
            }
        }
    }
}

// ---------------------------------------------------------------------------
__global__ __launch_bounds__(1024) void k_bias(
    const int* __restrict__ nodes, const float* __restrict__ lp,
    const float* __restrict__ ovl_emb, const float* __restrict__ alpha_p,
    float* __restrict__ bias)
{
    int b = blockIdx.x, tid = threadIdx.x;
    __shared__ int nd[32][32];
    __shared__ unsigned int bmv[32][17];
    __shared__ float lpc[32];
    __shared__ float emb[16];
    nd[tid >> 5][tid & 31] = nodes[b * 1024 + tid];
    if (tid < 512) bmv[tid >> 4][tid & 15] = 0u;
    if (tid < 32) {
        float l = finite_or_zero(lp[b * 32 + tid]);
        l = l < -30.f ? -30.f : (l > 0.f ? 0.f : l);
        lpc[tid] = l;
    }
    if (tid >= 64 && tid < 64 + KMAXC + 1) emb[tid - 64] = ovl_emb[tid - 64];
    __syncthreads();
    int own = nd[tid >> 5][tid & 31];
    if (own >= 0) atomicOr(&bmv[tid >> 5][own >> 5], 1u << (own & 31));
    __syncthreads();
    int i = tid >> 5, j = tid & 31;
    float alpha = alpha_p[0];
    int cnt = 0;
    #pragma unroll
    for (int k = 0; k < 32; ++k) {
        int nk = nd[i][k];
        if (nk >= 0) cnt += (int)((bmv[j][nk >> 5] >> (nk & 31)) & 1u);
    }
    bias[b * 1024 + tid] = emb[cnt > KMAXC ? KMAXC : cnt] - alpha * lpc[j];
}

// ---------------------------------------------------------------------------
// Fused LN1 + per-head qkv-slice GEMM + attention (R11 verified). Grid 256.
__global__ __launch_bounds__(256, 2) void k_attn_ln(
    const float* __restrict__ x, const float* __restrict__ biasb,
    const float* __restrict__ ln1_g, const float* __restrict__ ln1_b,
    const u16* __restrict__ qkvT, u16* __restrict__ ob)
{
    __shared__ __align__(16) float xf[32 * 260];
    __shared__ __align__(16) u16 rb[32 * 256];
    __shared__ __align__(16) float qs[32 * 68];
    __shared__ __align__(16) float ks[32 * 68];
    __shared__ __align__(16) float vs[32 * 68];
    __shared__ float sc[32 * 33];
    int tid = threadIdx.x, lane = tid & 63, wave = tid >> 6;
    int b = blockIdx.x >> 2, h = blockIdx.x & 3;
    int fr = lane & 15, quad = lane >> 4;

    #pragma unroll
    for (int u = 0; u < 8; ++u) {
        int v = u * 256 + tid;
        int i = v >> 6, c = (v & 63) * 4;
        *reinterpret_cast<float4*>(xf + i * 260 + c) =
            *reinterpret_cast<const float4*>(x + (size_t)(b * 32 + i) * 256 + c);
    }
    __syncthreads();
    #pragma unroll
    for (int rr = 0; rr < 8; ++rr) {
        int row = wave * 8 + rr;
        float4 xv = *reinterpret_cast<const float4*>(xf + row * 260 + lane * 4);
        float s = xv.x + xv.y + xv.z + xv.w;
        #pragma unroll
        for (int o2 = 32; o2 > 0; o2 >>= 1) s += __shfl_xor(s, o2);
        float mu = s * (1.0f / 256.0f);
        float d0 = xv.x - mu, d1 = xv.y - mu, d2 = xv.z - mu, d3 = xv.w - mu;
        float sq = d0 * d0 + d1 * d1 + d2 * d2 + d3 * d3;
        #pragma unroll
        for (int o2 = 32; o2 > 0; o2 >>= 1) sq += __shfl_xor(sq, o2);
        float rs = rsqrtf(sq * (1.0f / 256.0f) + 1e-5f);
        int c = lane * 4;
        float4 gv = *reinterpret_cast<const float4*>(ln1_g + c);
        float4 bv = *reinterpret_cast<const float4*>(ln1_b + c);
        ushort4 o = { f2us(d0 * rs * gv.x + bv.x), f2us(d1 * rs * gv.y + bv.y),
                      f2us(d2 * rs * gv.z + bv.z), f2us(d3 * rs * gv.w + bv.w) };
        *reinterpret_cast<ushort4*>(rb + row * 256 + (((c >> 3) ^ (row & 7)) * 8) + (c & 7)) = o;
    }
    __syncthreads();
    // qkv slice: 12 n-tiles (3/wave): nt 0-3 q, 4-7 k, 8-11 v.
    f32x4 acc[3][2];
    #pragma unroll
    for (int i = 0; i < 3; ++i) { acc[i][0] = (f32x4){0,0,0,0}; acc[i][1] = (f32x4){0,0,0,0}; }
    for (int kc = 0; kc < 8; ++kc) {
        bf16x8 wf[3], bfv[2];
        #pragma unroll
        for (int i = 0; i < 3; ++i) {
            int nt = wave * 3 + i;
            int wrow = (nt >> 2) * 256 + h * 64 + (nt & 3) * 16 + fr;
            wf[i] = *reinterpret_cast<const bf16x8*>(qkvT + (size_t)wrow * 256 + kc * 32 + quad * 8);
        }
        #pragma unroll
        for (int j = 0; j < 2; ++j) {
            int m = j * 16 + fr;
            bfv[j] = *reinterpret_cast<const bf16x8*>(rb + m * 256 + (((kc * 4 + quad) ^ (m & 7)) * 8));
        }
        #pragma unroll
        for (int i = 0; i < 3; ++i)
            #pragma unroll
            for (int j = 0; j < 2; ++j)
                acc[i][j] = __builtin_amdgcn_mfma_f32_16x16x32_bf16(wf[i], bfv[j], acc[i][j], 0, 0, 0);
    }
    #pragma unroll
    for (int i = 0; i < 3; ++i) {
        int nt = wave * 3 + i;
        int sec = nt >> 2;
        int nl = (nt & 3) * 16 + quad * 4;
        float* dst = (sec == 0) ? qs : ((sec == 1) ? ks : vs);
        #pragma unroll
        for (int j = 0; j < 2; ++j) {
            int m = j * 16 + fr;
            float4 o = { acc[i][j][0], acc[i][j][1], acc[i][j][2], acc[i][j][3] };
            *reinterpret_cast<float4*>(dst + m * 68 + nl) = o;
        }
    }
    __syncthreads();
    #pragma unroll
    for (int u = 0; u < 4; ++u) {
        int p = tid + u * 256;
        int i = p >> 5, j = p & 31;
        float s = 0.f;
        #pragma unroll
        for (int d = 0; d < 64; ++d) s += qs[i * 68 + d] * ks[j * 68 + d];
        sc[i * 33 + j] = s * 0.125f + biasb[b * 1024 + i * 32 + j];
    }
    __syncthreads();
    if (tid < 32) {
        int i = tid;
        float m = -1e30f;
        for (int j = 0; j < 32; ++j) m = fmaxf(m, sc[i * 33 + j]);
        float sum = 0.f;
        for (int j = 0; j < 32; ++j) { float e = expf(sc[i * 33 + j] - m); sc[i * 33 + j] = e; sum += e; }
        float inv = 1.0f / sum;
        for (int j = 0; j < 32; ++j) sc[i * 33 + j] *= inv;
    }
    __syncthreads();
    #pragma unroll
    for (int u = 0; u < 8; ++u) {
        int idx = tid + u * 256;
        int i = idx >> 6, d = idx & 63;
        float a = 0.f;
        #pragma unroll
        for (int j = 0; j < 32; ++j) a += sc[i * 33 + j] * vs[j * 68 + d];
        ob[(size_t)(b * 32 + i) * 256 + h * 64 + d] = f2us(a);
    }
}

// ---------------------------------------------------------------------------
// LN(X) @ BT^T, 32x64 tile, K=256, full B panel resident (R14 verified).
__global__ __launch_bounds__(256) void k_gemmA_ln(
    const float* __restrict__ X, const u16* __restrict__ BT,
    const float* __restrict__ ln_g, const float* __restrict__ ln_b,
    const float* __restrict__ bias, u16* __restrict__ C,
    int N, int act)
{
    __shared__ __align__(16) u16 As[32 * 256];
    __shared__ __align__(16) u16 Bs[64 * 256];
    int tid = threadIdx.x, lane = tid & 63, wave = tid >> 6;
    int wm = wave >> 1, wn = wave & 1;
    int bm = blockIdx.y * 32, bn = blockIdx.x * 64;
    int fr = lane & 15, quad = lane >> 4;

    #pragma unroll
    for (int t = 0; t < 8; ++t) {
        int v = t * 4 + wave;
        int r = v * 2 + (lane >> 5);
        int p = lane & 31;
        int cc = p ^ (r & 7);
        gll16(BT + (size_t)(bn + r) * 256 + cc * 8, Bs + v * 512);
    }
    #pragma unroll
    for (int rr = 0; rr < 8; ++rr) {
        int r = wave * 8 + rr;
        float4 xv = *reinterpret_cast<const float4*>(X + (size_t)(bm + r) * 256 + lane * 4);
        float s = xv.x + xv.y + xv.z + xv.w;
        #pragma unroll
        for (int o2 = 32; o2 > 0; o2 >>= 1) s += __shfl_xor(s, o2);
        float mu = s * (1.0f / 256.0f);
        float d0 = xv.x - mu, d1 = xv.y - mu, d2 = xv.z - mu, d3 = xv.w - mu;
        float sq = d0 * d0 + d1 * d1 + d2 * d2 + d3 * d3;
        #pragma unroll
        for (int o2 = 32; o2 > 0; o2 >>= 1) sq += __shfl_xor(sq, o2);
        float rs = rsqrtf(sq * (1.0f / 256.0f) + 1e-5f);
        int c = lane * 4;
        float4 gv = *reinterpret_cast<const float4*>(ln_g + c);
        float4 bv = *reinterpret_cast<const float4*>(ln_b + c);
        ushort4 o = { f2us(d0 * rs * gv.x + bv.x), f2us(d1 * rs * gv.y + bv.y),
                      f2us(d2 * rs * gv.z + bv.z), f2us(d3 * rs * gv.w + bv.w) };
        *reinterpret_cast<ushort4*>(As + r * 256 + (((lane >> 1) ^ (r & 7)) * 8) + (lane & 1) * 4) = o;
    }
    __syncthreads();

    f32x4 acc[2];
    acc[0] = (f32x4){0,0,0,0}; acc[1] = (f32x4){0,0,0,0};
    #pragma unroll
    for (int kc = 0; kc < 8; ++kc) {
        int am = wm * 16 + fr;
        bf16x8 af = *reinterpret_cast<const bf16x8*>(
            As + am * 256 + (((kc * 4 + quad) ^ (am & 7)) * 8));
        bf16x8 bfr[2];
        #pragma unroll
        for (int j = 0; j < 2; ++j) {
            int br = wn * 32 + j * 16 + fr;
            bfr[j] = *reinterpret_cast<const bf16x8*>(
                Bs + br * 256 + (((kc * 4 + quad) ^ (br & 7)) * 8));
        }
        acc[0] = __builtin_amdgcn_mfma_f32_16x16x32_bf16(af, bfr[0], acc[0], 0, 0, 0);
        acc[1] = __builtin_amdgcn_mfma_f32_16x16x32_bf16(af, bfr[1], acc[1], 0, 0, 0);
    }
    int crow0 = bm + wm * 16 + quad * 4;
    int ccol0 = bn + wn * 32 + fr;
    #pragma unroll
    for (int r = 0; r < 4; ++r) {
        int m = crow0 + r;
        #pragma unroll
        for (int j = 0; j < 2; ++j) {
            int n = ccol0 + j * 16;
            float v = acc[j][r];
            if (bias) v += bias[n];
            if (act == 2) v = 0.5f * v * (1.0f + erff(v * 0.70710678118654752f));
            C[(size_t)m * N + n] = f2us(v);
        }
    }
}

// ---------------------------------------------------------------------------
// bf16 GEMM 32x64 tile, paneled K, barrier-free inner loop (R14 verified).
__global__ __launch_bounds__(256) void k_gemmB(
    const u16* __restrict__ A, const u16* __restrict__ BT,
    const float* __restrict__ bias, float* __restrict__ Cout,
    const float* __restrict__ resid, int M, int K, int N)
{
    __shared__ __align__(16) u16 As[32 * 256];
    __shared__ __align__(16) u16 Bs[64 * 256];
    int tid = threadIdx.x, lane = tid & 63, wave = tid >> 6;
    int wm = wave >> 1, wn = wave & 1;
    int bm = blockIdx.y * 32, bn = blockIdx.x * 64;
    int fr = lane & 15, quad = lane >> 4;
    int npan = K >> 8;

    f32x4 acc[2];
    acc[0] = (f32x4){0,0,0,0}; acc[1] = (f32x4){0,0,0,0};
    for (int pan = 0; pan < npan; ++pan) {
        if (pan) __syncthreads();
        int kbase = pan * 256;
        #pragma unroll
        for (int t = 0; t < 4; ++t) {
            int v = t * 4 + wave;
            int r = v * 2 + (lane >> 5);
            int p = lane & 31;
            int cc = p ^ (r & 7);
            gll16(A + (size_t)(bm + r) * K + kbase + cc * 8, As + v * 512);
        }
        #pragma unroll
        for (int t = 0; t < 8; ++t) {
            int v = t * 4 + wave;
            int r = v * 2 + (lane >> 5);
            int p = lane & 31;
            int cc = p ^ (r & 7);
            gll16(BT + (size_t)(bn + r) * K + kbase + cc * 8, Bs + v * 512);
        }
        __syncthreads();
        #pragma unroll
        for (int kc = 0; kc < 8; ++kc) {
            int am = wm * 16 + fr;
            bf16x8 af = *reinterpret_cast<const bf16x8*>(
                As + am * 256 + (((kc * 4 + quad) ^ (am & 7)) * 8));
            bf16x8 bfr[2];
            #pragma unroll
            for (int j = 0; j < 2; ++j) {
                int br = wn * 32 + j * 16 + fr;
                bfr[j] = *reinterpret_cast<const bf16x8*>(
                    Bs + br * 256 + (((kc * 4 + quad) ^ (br & 7)) * 8));
            }
            acc[0] = __builtin_amdgcn_mfma_f32_16x16x32_bf16(af, bfr[0], acc[0], 0, 0, 0);
            acc[1] = __builtin_amdgcn_mfma_f32_16x16x32_bf16(af, bfr[1], acc[1], 0, 0, 0);
        }
    }
    int crow0 = bm + wm * 16 + quad * 4;
    int ccol0 = bn + wn * 32 + fr;
    #pragma unroll
    for (int r = 0; r < 4; ++r) {
        int m = crow0 + r;
        #pragma unroll
        for (int j = 0; j < 2; ++j) {
            int n = ccol0 + j * 16;
            Cout[(size_t)m * N + n] = acc[j][r] + bias[n] + resid[(size_t)m * N + n];
        }
    }
}

// ---------------------------------------------------------------------------
// Final LN + softmax(-lp_c)-weighted sum (verified R11 body).
__global__ __launch_bounds__(256) void k_fin(
    const float* __restrict__ x, const float* __restrict__ lp,
    const float* __restrict__ lnout_g, const float* __restrict__ lnout_b,
    float* __restrict__ out)
{
    __shared__ __align__(16) float xlnf[32 * 260];
    __shared__ float wfin[32];
    int tid = threadIdx.x, lane = tid & 63, wave = tid >> 6;
    int b = blockIdx.x;
    #pragma unroll
    for (int rr = 0; rr < 8; ++rr) {
        int row = wave * 8 + rr;
        float4 xv = *reinterpret_cast<const float4*>(x + (size_t)(b * 32 + row) * 256 + lane * 4);
        float s = xv.x + xv.y + xv.z + xv.w;
        #pragma unroll
        for (int o2 = 32; o2 > 0; o2 >>= 1) s += __shfl_xor(s, o2);
        float mu = s * (1.0f / 256.0f);
        float d0 = xv.x - mu, d1 = xv.y - mu, d2 = xv.z - mu, d3 = xv.w - mu;
        float sq = d0 * d0 + d1 * d1 + d2 * d2 + d3 * d3;
        #pragma unroll
        for (int o2 = 32; o2 > 0; o2 >>= 1) sq += __shfl_xor(sq, o2);
        float rs = rsqrtf(sq * (1.0f / 256.0f) + 1e-5f);
        int c = lane * 4;
        float4 gv = *reinterpret_cast<const float4*>(lnout_g + c);
        float4 bv = *reinterpret_cast<const float4*>(lnout_b + c);
        float4 o = { d0 * rs * gv.x + bv.x, d1 * rs * gv.y + bv.y,
                     d2 * rs * gv.z + bv.z, d3 * rs * gv.w + bv.w };
        *reinterpret_cast<float4*>(xlnf + row * 260 + c) = o;
    }
    __syncthreads();
    if (tid == 0) {
        float l2[32];
        float m = -1e30f;
        for (int i = 0; i < 32; ++i) {
            float l = finite_or_zero(lp[b * 32 + i]);
            l = l < -30.f ? -30.f : (l > 0.f ? 0.f : l);
            l2[i] = -l;
            m = fmaxf(m, -l);
        }
        float s = 0.f;
        for (int i = 0; i < 32; ++i) { float e = expf(l2[i] - m); wfin[i] = e; s += e; }
        float inv = 1.0f / s;
        for (int i = 0; i < 32; ++i) wfin[i] *= inv;
    }
    __syncthreads();
    float a = 0.f;
    for (int i = 0; i < 32; ++i) a += wfin[i] * xlnf[i * 260 + tid];
    out[(size_t)b * 256 + tid] = a;
}

// ---------------------------------------------------------------------------
extern "C" void kernel_launch(void* const* d_in, const int* in_sizes, int n_in,
                              void* d_out, int out_size, void* d_ws, size_t ws_size,
                              hipStream_t stream)
{
    const int*   x_ids    = (const int*)d_in[0];
    const int*   edge_ids = (const int*)d_in[1];
    const int*   srcp     = (const int*)d_in[2];
    const int*   dstp     = (const int*)d_in[3];
    const int*   nodes    = (const int*)d_in[4];
    const int*   dist     = (const int*)d_in[5];
    const float* lp       = (const float*)d_in[6];
    const float* atom_emb = (const float*)d_in[7];
    const float* bond_emb = (const float*)d_in[8];
    const float* dist_emb = (const float*)d_in[9];
    const float* logp_W   = (const float*)d_in[10];
    const float* logp_b   = (const float*)d_in[11];
    const float* gnn_eps  = (const float*)d_in[12];
    const float* gnn_W1   = (const float*)d_in[13];
    const float* gnn_b1   = (const float*)d_in[14];
    const float* gnn_W2   = (const float*)d_in[15];
    const float* gnn_b2   = (const float*)d_in[16];
    const float* ln1_g    = (const float*)d_in[17];
    const float* ln1_b    = (const float*)d_in[18];
    const float* qkv_W    = (const float*)d_in[19];
    const float* out_W    = (const float*)d_in[20];
    const float* out_b    = (const float*)d_in[21];
    const float* ln2_g    = (const float*)d_in[22];
    const float* ln2_b    = (const float*)d_in[23];
    const float* f1_W     = (const float*)d_in[24];
    const float* f1_b     = (const float*)d_in[25];
    const float* f2_W     = (const float*)d_in[26];
    const float* f2_b     = (const float*)d_in[27];
    const float* lnout_g  = (const float*)d_in[28];
    const float* lnout_b  = (const float*)d_in[29];
    const float* ovl_emb  = (const float*)d_in[30];
    const float* alpha    = (const float*)d_in[31];

    char* ws = (char*)d_ws;
    u16*   gW1T  = (u16*)(ws + 100663296ull);
    u16*   gW2T  = (u16*)(ws + 100663296ull + 524288ull);
    u16*   permW = (u16*)(ws + 100663296ull + 1048576ull);
    u16*   offW  = (u16*)(ws + 100663296ull + 1310720ull);
    u16*   qkvT  = (u16*)(ws + 33554432ull);
    u16*   outT  = (u16*)(ws + 33554432ull + 1572864ull);
    u16*   f1T   = (u16*)(ws + 33554432ull + 2097152ull);
    u16*   f2T   = (u16*)(ws + 33554432ull + 4194304ull);
    u16*   ob    = (u16*)(ws + 33554432ull + 6291456ull);
    float* biasb = (float*)(ws + 33554432ull + 7340032ull);
    u16*   ffh   = (u16*)(ws + 33554432ull + 10747904ull);
    float* x     = (float*)(ws + 67108864ull);

    k_csr<<<SSUB / 4, 256, 0, stream>>>(srcp, dstp, edge_ids, permW, offW);
    k_wtrans<<<dim3(8, 8, 4), 256, 0, stream>>>(gnn_W1, gW1T, 256, 256);
    k_wtrans<<<dim3(8, 8, 4), 256, 0, stream>>>(gnn_W2, gW2T, 256, 256);
    k_gnn4<<<NNODE / 64, 256, 0, stream>>>(
        x_ids, dist, nodes, lp, atom_emb, dist_emb, logp_W, logp_b,
        permW, offW, bond_emb, gnn_eps, gnn_b1, gnn_b2, gW1T, gW2T, x);
    k_wtrans<<<dim3(8, 24, 4), 256, 0, stream>>>(qkv_W, qkvT, 256, 768);
    k_wtrans<<<dim3(8, 8, 4), 256, 0, stream>>>(out_W, outT, 256, 256);
    k_wtrans<<<dim3(8, 32, 4), 256, 0, stream>>>(f1_W, f1T, 256, 1024);
    k_wtrans<<<dim3(32, 8, 4), 256, 0, stream>>>(f2_W, f2T, 1024, 256);
    k_bias<<<BATCH, 1024, 0, stream>>>(nodes, lp, ovl_emb, alpha, biasb);
    for (int t = 0; t < TLAY; ++t) {
        k_attn_ln<<<BATCH * NHEAD, 256, 0, stream>>>(
            x, biasb, ln1_g + t * 256, ln1_b + t * 256,
            qkvT + (size_t)t * 768 * 256, ob);
        k_gemmB<<<dim3(4, 64), 256, 0, stream>>>(
            ob, outT + (size_t)t * 65536, out_b + t * 256, x, x, SSUB, 256, 256);
        k_gemmA_ln<<<dim3(16, 64), 256, 0, stream>>>(
            x, f1T + (size_t)t * 1024 * 256, ln2_g + t * 256, ln2_b + t * 256,
            f1_b + t * 1024, ffh, 1024, 2);
        k_gemmB<<<dim3(4, 64), 256, 0, stream>>>(
            ffh, f2T + (size_t)t * 256 * 1024, f2_b + t * 256, x, x, SSUB, 1024, 256);
    }
    k_fin<<<BATCH, 256, 0, stream>>>(x, lp, lnout_g, lnout_b, (float*)d_out);
}